// Round 18
// baseline (151.767 us; speedup 1.0000x reference)
//
#include <hip/hip_runtime.h>
#include <hip/hip_bf16.h>

typedef __attribute__((ext_vector_type(8))) _Float16 hfrag;
typedef __attribute__((ext_vector_type(4))) float ffrag;
typedef __attribute__((ext_vector_type(8))) unsigned short us8;
typedef __attribute__((ext_vector_type(4))) unsigned short us4;

#define DEVINL static __device__ __forceinline__
#define MFMAH(a, b, c)  __builtin_amdgcn_mfma_f32_16x16x32_f16((a), (b), (c), 0, 0, 0)

// async global->LDS, 16B per lane; LDS dest = wave-uniform base + lane*16
DEVINL void gload_lds16(const _Float16* g, _Float16* l) {
    __builtin_amdgcn_global_load_lds(
        (const __attribute__((address_space(1))) unsigned int*)g,
        (__attribute__((address_space(3))) unsigned int*)l, 16, 0, 0);
}

DEVINL int pkh(float a, float b) {       // pack 2 f32 -> fp16x2 dword
    typedef __attribute__((ext_vector_type(2))) __fp16 fp16x2;
    fp16x2 t = __builtin_amdgcn_cvt_pkrtz(a, b);
    union { fp16x2 h; int i; } u; u.h = t; return u.i;
}

// V key-permutation within 32-element groups (split-k fragment mapping fix).
DEVINL int permV(int p) {
    return (p & 35) | ((p & 8) << 1) | ((p & 4) << 1) | ((p & 16) >> 2);
}

// ---------------------------------------------------------------------------
// Kernel 1: pack weights to fp16 [512][256], gather biases; zero cnt/stats.
// ---------------------------------------------------------------------------
__global__ void kprep(const float* __restrict__ Wq, const float* __restrict__ Wk,
                      const float* __restrict__ Wv, const float* __restrict__ bq,
                      const float* __restrict__ bk, const float* __restrict__ bv,
                      _Float16* __restrict__ Wh, float* __restrict__ ball,
                      int* __restrict__ cnt, float* __restrict__ stats) {
    int t = blockIdx.x * 256 + threadIdx.x;      // 512*256 threads
    int o = t >> 8, c = t & 255;
    float v = (o < 128) ? Wq[o * 256 + c]
            : (o < 256) ? Wk[(o - 128) * 256 + c]
                        : Wv[(o - 256) * 256 + c];
    Wh[t] = (_Float16)v;
    if (c == 0) {
        ball[o] = (o < 128) ? bq[o] : (o < 256) ? bk[o - 128] : bv[o - 256];
    }
    if (blockIdx.x == 0 && threadIdx.x < 128) cnt[threadIdx.x] = 0;
    if (blockIdx.x == 1) {
        stats[threadIdx.x] = 0.f;
        stats[256 + threadIdx.x] = 0.f;
    }
}

// ---------------------------------------------------------------------------
// Kernel 2: 1x1 conv projections via fp16 MFMA.
// Q,K written [b][n][128] fp16; V written [b][co][n] fp16 (operand swap),
// with key-index permV within 32-pixel groups.
// ---------------------------------------------------------------------------
__global__ __launch_bounds__(256) void kproj(const float* __restrict__ x,
                                             const _Float16* __restrict__ Wh,
                                             const float* __restrict__ ball,
                                             _Float16* __restrict__ Qb,
                                             _Float16* __restrict__ Kb,
                                             _Float16* __restrict__ Vb) {
    __shared__ _Float16 sX[64 * 256];             // [pixel][ch], XOR-swizzled, 32KB
    const int t = threadIdx.x;
    const int lane = t & 63;
    const int wv = t >> 6;
    const int l16 = lane & 15;
    const int lg = lane >> 4;
    const int b = blockIdx.x >> 6;
    const int n0 = (blockIdx.x & 63) << 6;
    const float* xb = x + (size_t)b * 256 * 4096 + n0;

    // stage x^T tile: thread = pixel p (=lane), channel group by wave
    const int p = lane;
#pragma unroll
    for (int ci = 0; ci < 8; ++ci) {
        const int c0 = ci * 32 + (wv << 3);
        __align__(16) _Float16 th[8];
#pragma unroll
        for (int j = 0; j < 8; ++j) th[j] = (_Float16)xb[(size_t)(c0 + j) * 4096 + p];
        *(us8*)&sX[p * 256 + (c0 ^ ((p & 7) << 3))] = *(const us8*)th;
    }
    __syncthreads();

    ffrag accQK[16];  // D[pixel 16*wv+..][o=16ct+l16], o in 0..255 (Q,K)
    ffrag accV[16];   // D[o=256+64*wv+16mt+..][pixel 16*c2+l16]
#pragma unroll
    for (int i = 0; i < 16; ++i) {
        accQK[i] = ffrag{0.f, 0.f, 0.f, 0.f};
        accV[i]  = ffrag{0.f, 0.f, 0.f, 0.f};
    }
    const int rowx = 16 * wv + l16;
#pragma unroll
    for (int step = 0; step < 8; ++step) {
        const int cb = step * 32 + (lg << 3);
        hfrag ax = *(const hfrag*)&sX[rowx * 256 + (cb ^ ((rowx & 7) << 3))];
#pragma unroll
        for (int ct = 0; ct < 16; ++ct) {
            const int o = ct * 16 + l16;
            hfrag bw = *(const hfrag*)&Wh[o * 256 + cb];
            accQK[ct] = MFMAH(ax, bw, accQK[ct]);
        }
        hfrag bx[4];
#pragma unroll
        for (int c2 = 0; c2 < 4; ++c2) {
            const int px = c2 * 16 + l16;
            bx[c2] = *(const hfrag*)&sX[px * 256 + (cb ^ ((px & 7) << 3))];
        }
#pragma unroll
        for (int mt = 0; mt < 4; ++mt) {
            const int o = 256 + 64 * wv + 16 * mt + l16;
            hfrag aw = *(const hfrag*)&Wh[o * 256 + cb];
#pragma unroll
            for (int c2 = 0; c2 < 4; ++c2)
                accV[mt * 4 + c2] = MFMAH(aw, bx[c2], accV[mt * 4 + c2]);
        }
    }

    // epilogue: +bias, fp16, store
#pragma unroll
    for (int ct = 0; ct < 16; ++ct) {
        const int o = ct * 16 + l16;
        const float bias = ball[o];
        _Float16* dst = (o < 128) ? Qb : Kb;
        const int oo = o & 127;
#pragma unroll
        for (int r = 0; r < 4; ++r) {
            const int px = 16 * wv + (lg << 2) + r;
            dst[((size_t)b * 4096 + n0 + px) * 128 + oo] = (_Float16)(accQK[ct][r] + bias);
        }
    }
#pragma unroll
    for (int mt = 0; mt < 4; ++mt) {
#pragma unroll
        for (int r = 0; r < 4; ++r) {
            const int o = 64 * wv + 16 * mt + (lg << 2) + r;
            const float bias = ball[256 + o];
#pragma unroll
            for (int c2 = 0; c2 < 4; ++c2) {
                const int px = c2 * 16 + l16;
                Vb[((size_t)b * 256 + o) * 4096 + n0 + permV(px)] =
                    (_Float16)(accV[mt * 4 + c2][r] + bias);
            }
        }
    }
}

// ---------------------------------------------------------------------------
// Kernel 3: fused flash attention + IN-KERNEL cross-block pair merge.
// Round-15 body (KEY-SPLIT, SWAPPED QK^T, 32q/wave, K/V dbuf, deferred-PV,
// setprio).  256 blocks x 512 threads, 1 block/CU (all co-resident).
// New tail: arrival-ordered split-k combine — first arriver of each
// (batch,q-tile) pair publishes pO/pML and exits; second arriver reads the
// partner tile, flash-combines against its LDS copy, writes merged w into
// the pO half0 slot, and atomically accumulates BN stats.
// ---------------------------------------------------------------------------
__global__ __launch_bounds__(512, 2) void kattn(const _Float16* __restrict__ Qb,
                                                const _Float16* __restrict__ Kb,
                                                const _Float16* __restrict__ Vb,
                                                _Float16* __restrict__ pO,
                                                float* __restrict__ pML,
                                                float* __restrict__ stats,
                                                int* __restrict__ cnt) {
    __shared__ __align__(16) _Float16 smem[50176];  // 98 KB
    // K0 @0 | K1 @8192 | V0 @16384 | V1 @32768 | sml @49152 | sWab @49664
    float* sml = (float*)(smem + 49152);            // [128] float2 (1KB)
    __shared__ int sWho;

    const int t = threadIdx.x;
    const int lane = t & 63;
    const int wv = t >> 6;        // 0..7
    const int qg = wv & 3;        // 32-row query group (0..3)
    const int kh = wv >> 2;       // 32-key half (0..1)
    const int l16 = lane & 15;
    const int lg = lane >> 4;

    const int blk = blockIdx.x;
    const int x8 = blk & 7;
    const int b = x8 >> 1;                          // batch per XCD pair
    const int ksel = x8 & 1;                        // key half per XCD
    const int qt5 = blk >> 3;                       // 0..31
    const int n0 = qt5 << 7;                        // 128 q-rows per block
    const int kb = ksel << 11;                      // key base (0 or 2048)

    const _Float16* Kg = Kb + (size_t)b * 4096 * 128;
    const _Float16* Vg = Vb + (size_t)b * 256 * 4096;

    // ---- Q fragments for both q-tiles (rows qg*32+l16 and qg*32+16+l16)
    hfrag aq0[4], aq1[4];
    {
        const size_t gq0 = ((size_t)b * 4096 + n0 + qg * 32 + l16) * 128;
        const size_t gq1 = gq0 + 16 * 128;
#pragma unroll
        for (int st = 0; st < 4; ++st) {
            aq0[st] = *(const hfrag*)&Qb[gq0 + st * 32 + lg * 8];
            aq1[st] = *(const hfrag*)&Qb[gq1 + st * 32 + lg * 8];
        }
    }

    float m0 = -3e38f, l0 = 0.f;      // q-row r0 = qg*32 + l16
    float m1 = -3e38f, l1 = 0.f;      // q-row r1 = r0 + 16
    ffrag O0[16], O1[16];             // O^T[co = ct*16+lg*4+r][q]
#pragma unroll
    for (int i = 0; i < 16; ++i) {
        O0[i] = ffrag{0.f, 0.f, 0.f, 0.f};
        O1[i] = ffrag{0.f, 0.f, 0.f, 0.f};
    }
    hfrag pb0p, pb1p;                 // P fragments of iter i-1 (deferred PV)

    // staging lane constants
    const int krow_in = lane >> 4;              // K: row-in-chunk (0..3)
    const int kcol = lane & 15;                 // K: col chunk index
    const int vrow_in = lane >> 3;              // V: row-in-chunk (0..7)
    const int vcol = lane & 7;                  // V: col chunk index

    auto STAGEK = [&](int it, int bsel) {
        const int k0 = kb + (it << 6);
        _Float16* sK = smem + (bsel << 13);
#pragma unroll
        for (int j = 0; j < 2; ++j) {
            const int c = 2 * wv + j;           // 0..15
            const int row = 4 * c + krow_in;
            gload_lds16(Kg + (size_t)(k0 + row) * 128 + ((kcol ^ (row & 7)) << 3),
                        sK + c * 512);
        }
    };
    auto STAGEV = [&](int it, int bsel) {
        const int k0 = kb + (it << 6);
        _Float16* sV = smem + 16384 + (bsel << 14);
#pragma unroll
        for (int j = 0; j < 4; ++j) {
            const int cv = 4 * wv + j;          // 0..31
            const int co = 8 * cv + vrow_in;
            gload_lds16(Vg + (size_t)co * 4096 + k0 + ((vcol ^ (co & 7)) << 3),
                        sV + cv * 512);
        }
    };

    auto PV = [&](int bsel) {
        const _Float16* sV = smem + 16384 + (bsel << 14);
#pragma unroll
        for (int ct = 0; ct < 16; ++ct) {
            const int co = ct * 16 + l16;
            hfrag av = *(const hfrag*)&sV[co * 64 + ((kh * 32 + lg * 8) ^ ((co & 7) << 3))];
            O0[ct] = MFMAH(av, pb0p, O0[ct]);
            O1[ct] = MFMAH(av, pb1p, O1[ct]);
        }
    };

    // ---- prologue: stage K(0), V(0) into buf0
    STAGEK(0, 0);
    STAGEV(0, 0);
    __builtin_amdgcn_sched_barrier(0);

#pragma unroll 1
    for (int it = 0; it < 32; ++it) {
        asm volatile("s_waitcnt vmcnt(4)" ::: "memory");   // K(it) [+V(it-1)] landed
        __builtin_amdgcn_s_barrier();
        __builtin_amdgcn_sched_barrier(0);
        STAGEK((it + 1) & 31, (it + 1) & 1);               // early K prefetch
        __builtin_amdgcn_sched_barrier(0);

        const _Float16* sK = smem + ((it & 1) << 13);

        __builtin_amdgcn_s_setprio(1);
        ffrag S00 = ffrag{0.f,0.f,0.f,0.f}, S01 = ffrag{0.f,0.f,0.f,0.f};
        ffrag S10 = ffrag{0.f,0.f,0.f,0.f}, S11 = ffrag{0.f,0.f,0.f,0.f};
#pragma unroll
        for (int kt = 0; kt < 2; ++kt) {
            const int rowk = kh * 32 + kt * 16 + l16;
            const int swz = (rowk & 7) << 3;
#pragma unroll
            for (int st = 0; st < 4; ++st) {
                hfrag ak = *(const hfrag*)&sK[rowk * 128 + ((st * 32 + lg * 8) ^ swz)];
                if (kt == 0) {
                    S00 = MFMAH(ak, aq0[st], S00);
                    S10 = MFMAH(ak, aq1[st], S10);
                } else {
                    S01 = MFMAH(ak, aq0[st], S01);
                    S11 = MFMAH(ak, aq1[st], S11);
                }
            }
        }
        if (it > 0) PV((it - 1) & 1);
        __builtin_amdgcn_s_setprio(0);

        // ---- online softmax per q-row (2 rows/lane), defer-max THR=8
        float mx0 = fmaxf(fmaxf(fmaxf(S00[0], S00[1]), fmaxf(S00[2], S00[3])),
                          fmaxf(fmaxf(S01[0], S01[1]), fmaxf(S01[2], S01[3])));
        float mx1 = fmaxf(fmaxf(fmaxf(S10[0], S10[1]), fmaxf(S10[2], S10[3])),
                          fmaxf(fmaxf(S11[0], S11[1]), fmaxf(S11[2], S11[3])));
        mx0 = fmaxf(mx0, __shfl_xor(mx0, 16));
        mx0 = fmaxf(mx0, __shfl_xor(mx0, 32));
        mx1 = fmaxf(mx1, __shfl_xor(mx1, 16));
        mx1 = fmaxf(mx1, __shfl_xor(mx1, 32));
        if (__any((mx0 > m0 + 8.f) || (mx1 > m1 + 8.f))) {   // rare
            const float nm0 = fmaxf(m0, mx0), nm1 = fmaxf(m1, mx1);
            const float sc0 = __expf(m0 - nm0), sc1 = __expf(m1 - nm1);
            m0 = nm0; m1 = nm1;
            l0 *= sc0; l1 *= sc1;
#pragma unroll
            for (int i = 0; i < 16; ++i) {
#pragma unroll
                for (int r = 0; r < 4; ++r) {
                    O0[i][r] *= sc0;
                    O1[i][r] *= sc1;
                }
            }
        }
        float e00[4], e01[4], e10[4], e11[4];
        float rs0 = 0.f, rs1 = 0.f;
#pragma unroll
        for (int r = 0; r < 4; ++r) {
            e00[r] = __expf(S00[r] - m0);
            e01[r] = __expf(S01[r] - m0);
            e10[r] = __expf(S10[r] - m1);
            e11[r] = __expf(S11[r] - m1);
            rs0 += e00[r] + e01[r];
            rs1 += e10[r] + e11[r];
        }
        rs0 += __shfl_xor(rs0, 16);
        rs0 += __shfl_xor(rs0, 32);
        rs1 += __shfl_xor(rs1, 16);
        rs1 += __shfl_xor(rs1, 32);
        l0 += rs0;
        l1 += rs1;

        {
            union { int i[4]; hfrag h; } u;
            u.i[0] = pkh(e00[0], e00[1]);
            u.i[1] = pkh(e00[2], e00[3]);
            u.i[2] = pkh(e01[0], e01[1]);
            u.i[3] = pkh(e01[2], e01[3]);
            pb0p = u.h;
            u.i[0] = pkh(e10[0], e10[1]);
            u.i[1] = pkh(e10[2], e10[3]);
            u.i[2] = pkh(e11[0], e11[1]);
            u.i[3] = pkh(e11[2], e11[3]);
            pb1p = u.h;
        }

        __builtin_amdgcn_s_barrier();      // V((it-1)&1) reads done
        __builtin_amdgcn_sched_barrier(0);
        STAGEV((it + 1) & 31, (it + 1) & 1);               // late V prefetch
        __builtin_amdgcn_sched_barrier(0);
    }

    // ---- drain wrapped stages, then final PV(31)
    asm volatile("s_waitcnt vmcnt(0)" ::: "memory");
    __builtin_amdgcn_s_barrier();
    PV(1);                                                 // it=31 -> V buf 1

    // ---- epilogue: kh merge via fp16 LDS overlay, write pO/pML ----
    __syncthreads();
    _Float16* sE = smem;               // [128 row][256 col] fp16, col XOR-swizzled
    const int r0 = qg * 32 + l16;      // this lane's q-rows (0..127)
    const int r1 = r0 + 16;
    const int rsw0 = (r0 & 7) << 3;
    const int rsw1 = (r1 & 7) << 3;
    if (kh == 1) {
        const float inv0 = 1.f / l0, inv1 = 1.f / l1;
#pragma unroll
        for (int ct = 0; ct < 16; ++ct)
#pragma unroll
            for (int r = 0; r < 4; ++r) {
                const int col = ct * 16 + lg * 4 + r;
                sE[r0 * 256 + (col ^ rsw0)] = (_Float16)(O0[ct][r] * inv0);
                sE[r1 * 256 + (col ^ rsw1)] = (_Float16)(O1[ct][r] * inv1);
            }
        if (lg == 0) {
            ((float2*)sml)[r0] = make_float2(m0, l0);
            ((float2*)sml)[r1] = make_float2(m1, l1);
        }
    }
    __syncthreads();
    const size_t mlbase = (size_t)(ksel * 4 + b) * 4096 + n0;
    if (kh == 0) {
        const float2 pml0 = ((const float2*)sml)[r0];
        const float2 pml1 = ((const float2*)sml)[r1];
        const float M0 = fmaxf(m0, pml0.x), M1 = fmaxf(m1, pml1.x);
        const float a0 = __expf(m0 - M0), c0 = __expf(pml0.x - M0);
        const float a1 = __expf(m1 - M1), c1 = __expf(pml1.x - M1);
        const float nl0 = a0 * l0 + c0 * pml0.y;
        const float nl1 = a1 * l1 + c1 * pml1.y;
        const float wa0 = a0 / nl0, wb0 = c0 * pml0.y / nl0;
        const float wa1 = a1 / nl1, wb1 = c1 * pml1.y / nl1;
        if (lg == 0) {
            ((float2*)pML)[mlbase + r0] = make_float2(M0, nl0);
            ((float2*)pML)[mlbase + r1] = make_float2(M1, nl1);
        }
#pragma unroll
        for (int ct = 0; ct < 16; ++ct)
#pragma unroll
            for (int r = 0; r < 4; ++r) {
                const int col = ct * 16 + lg * 4 + r;
                const int i0 = r0 * 256 + (col ^ rsw0);
                const int i1 = r1 * 256 + (col ^ rsw1);
                const float v0 = (float)sE[i0];
                const float v1 = (float)sE[i1];
                sE[i0] = (_Float16)(wa0 * O0[ct][r] + wb0 * v0);
                sE[i1] = (_Float16)(wa1 * O1[ct][r] + wb1 * v1);
            }
    }
    __syncthreads();
    // ---- cooperative coalesced 16B store of the 64KB tile (unswizzle)
    const size_t obase = ((size_t)(ksel * 4 + b) * 4096 + n0) * 256;
#pragma unroll
    for (int i = 0; i < 8; ++i) {
        const int idx = i * 512 + t;            // 0..4095
        const int px = idx >> 5;                // 0..127
        const int cg8 = idx & 31;               // col-group of 8
        *(us8*)&pO[obase + (size_t)px * 256 + cg8 * 8] =
            *(const us8*)&sE[px * 256 + (cg8 ^ (px & 7)) * 8];
    }

    // ---- arrival-ordered cross-block pair merge ----
    __syncthreads();                            // all pO/pML stores issued
    if (t == 0) {
        __threadfence();                        // release pO/pML device-wide
        sWho = atomicAdd(&cnt[blk >> 1], 1);
    }
    __syncthreads();
    if (sWho == 0) return;                      // first arriver done
    if (t == 0) __threadfence();                // acquire partner data
    __syncthreads();

    // per-row combine weights (wa = partner, wc = own)
    float* sWab = (float*)(smem + 49664);       // [128] float2
    const size_t mlbaseP = (size_t)((ksel ^ 1) * 4 + b) * 4096 + n0;
    if (t < 128) {
        const float2 mlP = ((const float2*)pML)[mlbaseP + t];
        const float2 mlO = ((const float2*)pML)[mlbase + t];
        const float M = fmaxf(mlP.x, mlO.x);
        const float a = __expf(mlP.x - M) * mlP.y;
        const float c = __expf(mlO.x - M) * mlO.y;
        const float inv = 1.f / (a + c);
        ((float2*)sWab)[t] = make_float2(a * inv, c * inv);
    }
    __syncthreads();

    // merge elements, accumulate BN sums, write merged w into pO half0 slot
    const size_t gbaseP = mlbaseP * 256;
    const size_t gbase0 = ((size_t)b * 4096 + n0) * 256;
    float s[8], s2[8];
#pragma unroll
    for (int j = 0; j < 8; ++j) { s[j] = 0.f; s2[j] = 0.f; }
    const int cg8 = t & 31;
#pragma unroll 2
    for (int i = 0; i < 8; ++i) {
        const int px = i * 16 + (t >> 5);
        const float2 wab = ((const float2*)sWab)[px];
        hfrag po = *(const hfrag*)&pO[gbaseP + (size_t)px * 256 + cg8 * 8];
        hfrag ow = *(const hfrag*)&sE[px * 256 + (cg8 ^ (px & 7)) * 8];
        hfrag w;
#pragma unroll
        for (int j = 0; j < 8; ++j) {
            const float v = wab.x * (float)po[j] + wab.y * (float)ow[j];
            w[j] = (_Float16)v;
            s[j] += v;
            s2[j] += v * v;
        }
        *(hfrag*)&pO[gbase0 + (size_t)px * 256 + cg8 * 8] = w;
    }

    // BN partial reduce in LDS, then device atomics (stats zeroed by kprep)
    __syncthreads();                            // sE reads done; reuse as sacc
    float* sacc  = (float*)smem;                // [16][256]
    float* sacc2 = sacc + 4096;                 // [16][256]
    const int rg = t >> 5;
#pragma unroll
    for (int j = 0; j < 8; ++j) {
        sacc [rg * 256 + cg8 * 8 + j] = s[j];
        sacc2[rg * 256 + cg8 * 8 + j] = s2[j];
    }
    __syncthreads();
    {
        const int ch = t & 255;
        const int sel = t >> 8;                 // 0 or 1
        const float* src = sel ? sacc2 : sacc;
        float sum = 0.f;
#pragma unroll
        for (int rg2 = 0; rg2 < 16; ++rg2) sum += src[rg2 * 256 + ch];
        atomicAdd(&stats[sel * 256 + ch], sum);
    }
}

// ---------------------------------------------------------------------------
// Kernel 5: apply BN + transpose [b][n][co] -> out[b][co][n] fp32.
// w read from pO half0 (merged in kattn).
// ---------------------------------------------------------------------------
__global__ __launch_bounds__(256) void kapply(const _Float16* __restrict__ w,
                                              const float* __restrict__ stats,
                                              const float* __restrict__ gamma,
                                              const float* __restrict__ beta,
                                              float* __restrict__ out) {
    __shared__ _Float16 sw[64 * 260];           // 64 rows, pad 256->260
    __shared__ float sscale[256];
    __shared__ float sshift[256];
    const int t = threadIdx.x;
    const int b = blockIdx.x >> 6;
    const int n0 = (blockIdx.x & 63) << 6;
    const _Float16* wb = w + ((size_t)b * 4096 + n0) * 256;
#pragma unroll
    for (int i = 0; i < 16; ++i) {
        const int chunk = i * 256 + t;
        const int p = chunk >> 6;
        const int cq = chunk & 63;
        *(us4*)&sw[p * 260 + cq * 4] = *(const us4*)&wb[p * 256 + cq * 4];
    }
    {
        const float mean = stats[t] * (1.f / 16384.f);
        const float var = stats[256 + t] * (1.f / 16384.f) - mean * mean;
        const float inv = rsqrtf(var + 1e-5f);
        const float sc = gamma[t] * inv;
        sscale[t] = sc;
        sshift[t] = beta[t] - mean * sc;
    }
    __syncthreads();
    const int p = t & 63;
    const int cg = t >> 6;
    float* ob = out + (size_t)b * 256 * 4096 + n0;
#pragma unroll 4
    for (int i = 0; i < 64; ++i) {
        const int co = i * 4 + cg;
        const float v = (float)sw[p * 260 + co];
        ob[(size_t)co * 4096 + p] = v * sscale[co] + sshift[co];
    }
}

// ---------------------------------------------------------------------------
extern "C" void kernel_launch(void* const* d_in, const int* in_sizes, int n_in,
                              void* d_out, int out_size, void* d_ws, size_t ws_size,
                              hipStream_t stream) {
    const float* x     = (const float*)d_in[0];
    const float* Wq    = (const float*)d_in[1];
    const float* bq    = (const float*)d_in[2];
    const float* Wk    = (const float*)d_in[3];
    const float* bk    = (const float*)d_in[4];
    const float* Wv    = (const float*)d_in[5];
    const float* bv    = (const float*)d_in[6];
    const float* gamma = (const float*)d_in[7];
    const float* beta  = (const float*)d_in[8];
    float* out = (float*)d_out;

    char* ws = (char*)d_ws;
    // lifetimes: Wh/ball [kprep->kproj]; pML aliases Wh [kattn->kapply];
    // Qb/Kb [kproj->kattn]; merged w lives in pO half0 [kattn->kapply].
    _Float16* Wh    = (_Float16*)(ws + 0x0);        // 256 KB
    float*    pML   = (float*)(ws + 0x0);           // 256 KB (2x4x4096 float2)
    float*    ball  = (float*)(ws + 0x40000);       // 2 KB
    float*    stats = (float*)(ws + 0x40800);       // 2 KB
    int*      cnt   = (int*)(ws + 0x41000);         // 512 B (128 pair counters)
    _Float16* Qb    = (_Float16*)(ws + 0x100000);   // 4 MB
    _Float16* Kb    = (_Float16*)(ws + 0x500000);   // 4 MB
    _Float16* Vb    = (_Float16*)(ws + 0x900000);   // 8 MB
    _Float16* pO    = (_Float16*)(ws + 0x1100000);  // 16 MB (2x4x4096x256 fp16)
    if (ws_size < 0x2100000) return;  // 33 MB scratch (verified available)

    kprep<<<512, 256, 0, stream>>>(Wq, Wk, Wv, bq, bk, bv, Wh, ball, cnt, stats);
    kproj<<<256, 256, 0, stream>>>(x, Wh, ball, Qb, Kb, Vb);
    kattn<<<256, 512, 0, stream>>>(Qb, Kb, Vb, pO, pML, stats, cnt);
    kapply<<<256, 256, 0, stream>>>(pO, stats, gamma, beta, out);
}

// Round 19
// 143.952 us; speedup vs baseline: 1.0543x; 1.0543x over previous
//
#include <hip/hip_runtime.h>
#include <hip/hip_bf16.h>

typedef __attribute__((ext_vector_type(8))) _Float16 hfrag;
typedef __attribute__((ext_vector_type(4))) float ffrag;
typedef __attribute__((ext_vector_type(8))) unsigned short us8;
typedef __attribute__((ext_vector_type(4))) unsigned short us4;

#define DEVINL static __device__ __forceinline__
#define MFMAH(a, b, c)  __builtin_amdgcn_mfma_f32_16x16x32_f16((a), (b), (c), 0, 0, 0)

// async global->LDS, 16B per lane; LDS dest = wave-uniform base + lane*16
DEVINL void gload_lds16(const _Float16* g, _Float16* l) {
    __builtin_amdgcn_global_load_lds(
        (const __attribute__((address_space(1))) unsigned int*)g,
        (__attribute__((address_space(3))) unsigned int*)l, 16, 0, 0);
}

DEVINL int pkh(float a, float b) {       // pack 2 f32 -> fp16x2 dword
    typedef __attribute__((ext_vector_type(2))) __fp16 fp16x2;
    fp16x2 t = __builtin_amdgcn_cvt_pkrtz(a, b);
    union { fp16x2 h; int i; } u; u.h = t; return u.i;
}

// V key-permutation within 32-element groups (split-k fragment mapping fix).
DEVINL int permV(int p) {
    return (p & 35) | ((p & 8) << 1) | ((p & 4) << 1) | ((p & 16) >> 2);
}

// ---------------------------------------------------------------------------
// Kernel 1: pack weights to fp16 [512][256], gather biases; zero stats.
// ---------------------------------------------------------------------------
__global__ void kprep(const float* __restrict__ Wq, const float* __restrict__ Wk,
                      const float* __restrict__ Wv, const float* __restrict__ bq,
                      const float* __restrict__ bk, const float* __restrict__ bv,
                      _Float16* __restrict__ Wh, float* __restrict__ ball,
                      float* __restrict__ stats) {
    int t = blockIdx.x * 256 + threadIdx.x;      // 512*256 threads
    int o = t >> 8, c = t & 255;
    float v = (o < 128) ? Wq[o * 256 + c]
            : (o < 256) ? Wk[(o - 128) * 256 + c]
                        : Wv[(o - 256) * 256 + c];
    Wh[t] = (_Float16)v;
    if (c == 0) {
        ball[o] = (o < 128) ? bq[o] : (o < 256) ? bk[o - 128] : bv[o - 256];
    }
    if (blockIdx.x == 0) {
        stats[threadIdx.x] = 0.f;
        stats[256 + threadIdx.x] = 0.f;
    }
}

// ---------------------------------------------------------------------------
// Kernel 2: 1x1 conv projections via fp16 MFMA.
// Q,K written [b][n][128] fp16; V written [b][co][n] fp16 (operand swap),
// with key-index permV within 32-pixel groups.
// ---------------------------------------------------------------------------
__global__ __launch_bounds__(256) void kproj(const float* __restrict__ x,
                                             const _Float16* __restrict__ Wh,
                                             const float* __restrict__ ball,
                                             _Float16* __restrict__ Qb,
                                             _Float16* __restrict__ Kb,
                                             _Float16* __restrict__ Vb) {
    __shared__ _Float16 sX[64 * 256];             // [pixel][ch], XOR-swizzled, 32KB
    const int t = threadIdx.x;
    const int lane = t & 63;
    const int wv = t >> 6;
    const int l16 = lane & 15;
    const int lg = lane >> 4;
    const int b = blockIdx.x >> 6;
    const int n0 = (blockIdx.x & 63) << 6;
    const float* xb = x + (size_t)b * 256 * 4096 + n0;

    // stage x^T tile: thread = pixel p (=lane), channel group by wave
    const int p = lane;
#pragma unroll
    for (int ci = 0; ci < 8; ++ci) {
        const int c0 = ci * 32 + (wv << 3);
        __align__(16) _Float16 th[8];
#pragma unroll
        for (int j = 0; j < 8; ++j) th[j] = (_Float16)xb[(size_t)(c0 + j) * 4096 + p];
        *(us8*)&sX[p * 256 + (c0 ^ ((p & 7) << 3))] = *(const us8*)th;
    }
    __syncthreads();

    ffrag accQK[16];  // D[pixel 16*wv+..][o=16ct+l16], o in 0..255 (Q,K)
    ffrag accV[16];   // D[o=256+64*wv+16mt+..][pixel 16*c2+l16]
#pragma unroll
    for (int i = 0; i < 16; ++i) {
        accQK[i] = ffrag{0.f, 0.f, 0.f, 0.f};
        accV[i]  = ffrag{0.f, 0.f, 0.f, 0.f};
    }
    const int rowx = 16 * wv + l16;
#pragma unroll
    for (int step = 0; step < 8; ++step) {
        const int cb = step * 32 + (lg << 3);
        hfrag ax = *(const hfrag*)&sX[rowx * 256 + (cb ^ ((rowx & 7) << 3))];
#pragma unroll
        for (int ct = 0; ct < 16; ++ct) {
            const int o = ct * 16 + l16;
            hfrag bw = *(const hfrag*)&Wh[o * 256 + cb];
            accQK[ct] = MFMAH(ax, bw, accQK[ct]);
        }
        hfrag bx[4];
#pragma unroll
        for (int c2 = 0; c2 < 4; ++c2) {
            const int px = c2 * 16 + l16;
            bx[c2] = *(const hfrag*)&sX[px * 256 + (cb ^ ((px & 7) << 3))];
        }
#pragma unroll
        for (int mt = 0; mt < 4; ++mt) {
            const int o = 256 + 64 * wv + 16 * mt + l16;
            hfrag aw = *(const hfrag*)&Wh[o * 256 + cb];
#pragma unroll
            for (int c2 = 0; c2 < 4; ++c2)
                accV[mt * 4 + c2] = MFMAH(aw, bx[c2], accV[mt * 4 + c2]);
        }
    }

    // epilogue: +bias, fp16, store
#pragma unroll
    for (int ct = 0; ct < 16; ++ct) {
        const int o = ct * 16 + l16;
        const float bias = ball[o];
        _Float16* dst = (o < 128) ? Qb : Kb;
        const int oo = o & 127;
#pragma unroll
        for (int r = 0; r < 4; ++r) {
            const int px = 16 * wv + (lg << 2) + r;
            dst[((size_t)b * 4096 + n0 + px) * 128 + oo] = (_Float16)(accQK[ct][r] + bias);
        }
    }
#pragma unroll
    for (int mt = 0; mt < 4; ++mt) {
#pragma unroll
        for (int r = 0; r < 4; ++r) {
            const int o = 64 * wv + 16 * mt + (lg << 2) + r;
            const float bias = ball[256 + o];
#pragma unroll
            for (int c2 = 0; c2 < 4; ++c2) {
                const int px = c2 * 16 + l16;
                Vb[((size_t)b * 256 + o) * 4096 + n0 + permV(px)] =
                    (_Float16)(accV[mt * 4 + c2][r] + bias);
            }
        }
    }
}

// ---------------------------------------------------------------------------
// Kernel 3: fused flash attention (round-15 best: ~80 us).
// KEY-SPLIT, SWAPPED QK^T, 32q/wave, full K/V dbuf + deferred-PV + setprio.
// 256 blocks x 512 threads = 4 batches x 32 q-tiles(128 rows) x 2 key-halves.
// ---------------------------------------------------------------------------
__global__ __launch_bounds__(512, 2) void kattn(const _Float16* __restrict__ Qb,
                                                const _Float16* __restrict__ Kb,
                                                const _Float16* __restrict__ Vb,
                                                _Float16* __restrict__ pO,
                                                float* __restrict__ pML) {
    __shared__ __align__(16) _Float16 smem[49664];  // 97 KB
    // K0 @0 | K1 @8192 | V0 @16384 | V1 @32768 | sml @49152
    float* sml = (float*)(smem + 49152);            // [128] float2 (1KB)

    const int t = threadIdx.x;
    const int lane = t & 63;
    const int wv = t >> 6;        // 0..7
    const int qg = wv & 3;        // 32-row query group (0..3)
    const int kh = wv >> 2;       // 32-key half (0..1)
    const int l16 = lane & 15;
    const int lg = lane >> 4;

    const int blk = blockIdx.x;
    const int x8 = blk & 7;
    const int b = x8 >> 1;                          // batch per XCD pair
    const int ksel = x8 & 1;                        // key half per XCD
    const int qt5 = blk >> 3;                       // 0..31
    const int n0 = qt5 << 7;                        // 128 q-rows per block
    const int kb = ksel << 11;                      // key base (0 or 2048)

    const _Float16* Kg = Kb + (size_t)b * 4096 * 128;
    const _Float16* Vg = Vb + (size_t)b * 256 * 4096;

    // ---- Q fragments for both q-tiles (rows qg*32+l16 and qg*32+16+l16)
    hfrag aq0[4], aq1[4];
    {
        const size_t gq0 = ((size_t)b * 4096 + n0 + qg * 32 + l16) * 128;
        const size_t gq1 = gq0 + 16 * 128;
#pragma unroll
        for (int st = 0; st < 4; ++st) {
            aq0[st] = *(const hfrag*)&Qb[gq0 + st * 32 + lg * 8];
            aq1[st] = *(const hfrag*)&Qb[gq1 + st * 32 + lg * 8];
        }
    }

    float m0 = -3e38f, l0 = 0.f;      // q-row r0 = qg*32 + l16
    float m1 = -3e38f, l1 = 0.f;      // q-row r1 = r0 + 16
    ffrag O0[16], O1[16];             // O^T[co = ct*16+lg*4+r][q]
#pragma unroll
    for (int i = 0; i < 16; ++i) {
        O0[i] = ffrag{0.f, 0.f, 0.f, 0.f};
        O1[i] = ffrag{0.f, 0.f, 0.f, 0.f};
    }
    hfrag pb0p, pb1p;                 // P fragments of iter i-1 (deferred PV)

    // staging lane constants
    const int krow_in = lane >> 4;              // K: row-in-chunk (0..3)
    const int kcol = lane & 15;                 // K: col chunk index
    const int vrow_in = lane >> 3;              // V: row-in-chunk (0..7)
    const int vcol = lane & 7;                  // V: col chunk index

    // stage K tile `it` into K buf bsel: 2 loads/wave
    auto STAGEK = [&](int it, int bsel) {
        const int k0 = kb + (it << 6);
        _Float16* sK = smem + (bsel << 13);
#pragma unroll
        for (int j = 0; j < 2; ++j) {
            const int c = 2 * wv + j;           // 0..15
            const int row = 4 * c + krow_in;
            gload_lds16(Kg + (size_t)(k0 + row) * 128 + ((kcol ^ (row & 7)) << 3),
                        sK + c * 512);
        }
    };
    // stage V tile `it` into V buf bsel: 4 loads/wave
    auto STAGEV = [&](int it, int bsel) {
        const int k0 = kb + (it << 6);
        _Float16* sV = smem + 16384 + (bsel << 14);
#pragma unroll
        for (int j = 0; j < 4; ++j) {
            const int cv = 4 * wv + j;          // 0..31
            const int co = 8 * cv + vrow_in;
            gload_lds16(Vg + (size_t)co * 4096 + k0 + ((vcol ^ (co & 7)) << 3),
                        sV + cv * 512);
        }
    };

    // deferred PV: O += V(it-1) P(it-1)^T  (reads V buf (it-1)&1)
    auto PV = [&](int bsel) {
        const _Float16* sV = smem + 16384 + (bsel << 14);
#pragma unroll
        for (int ct = 0; ct < 16; ++ct) {
            const int co = ct * 16 + l16;
            hfrag av = *(const hfrag*)&sV[co * 64 + ((kh * 32 + lg * 8) ^ ((co & 7) << 3))];
            O0[ct] = MFMAH(av, pb0p, O0[ct]);
            O1[ct] = MFMAH(av, pb1p, O1[ct]);
        }
    };

    // ---- prologue: stage K(0), V(0) into buf0
    STAGEK(0, 0);
    STAGEV(0, 0);
    __builtin_amdgcn_sched_barrier(0);

#pragma unroll 1
    for (int it = 0; it < 32; ++it) {
        asm volatile("s_waitcnt vmcnt(4)" ::: "memory");   // K(it) [+V(it-1)] landed
        __builtin_amdgcn_s_barrier();
        __builtin_amdgcn_sched_barrier(0);
        STAGEK((it + 1) & 31, (it + 1) & 1);               // early K prefetch
        __builtin_amdgcn_sched_barrier(0);

        const _Float16* sK = smem + ((it & 1) << 13);

        __builtin_amdgcn_s_setprio(1);
        // ---- S^T = K Q^T, 2 q-tiles share each K fragment
        ffrag S00 = ffrag{0.f,0.f,0.f,0.f}, S01 = ffrag{0.f,0.f,0.f,0.f};
        ffrag S10 = ffrag{0.f,0.f,0.f,0.f}, S11 = ffrag{0.f,0.f,0.f,0.f};
#pragma unroll
        for (int kt = 0; kt < 2; ++kt) {
            const int rowk = kh * 32 + kt * 16 + l16;
            const int swz = (rowk & 7) << 3;
#pragma unroll
            for (int st = 0; st < 4; ++st) {
                hfrag ak = *(const hfrag*)&sK[rowk * 128 + ((st * 32 + lg * 8) ^ swz)];
                if (kt == 0) {
                    S00 = MFMAH(ak, aq0[st], S00);
                    S10 = MFMAH(ak, aq1[st], S10);
                } else {
                    S01 = MFMAH(ak, aq0[st], S01);
                    S11 = MFMAH(ak, aq1[st], S11);
                }
            }
        }
        // ---- deferred PV(it-1): MFMA cluster independent of softmax(it)
        if (it > 0) PV((it - 1) & 1);
        __builtin_amdgcn_s_setprio(0);

        // ---- online softmax per q-row (2 rows/lane), defer-max THR=8
        float mx0 = fmaxf(fmaxf(fmaxf(S00[0], S00[1]), fmaxf(S00[2], S00[3])),
                          fmaxf(fmaxf(S01[0], S01[1]), fmaxf(S01[2], S01[3])));
        float mx1 = fmaxf(fmaxf(fmaxf(S10[0], S10[1]), fmaxf(S10[2], S10[3])),
                          fmaxf(fmaxf(S11[0], S11[1]), fmaxf(S11[2], S11[3])));
        mx0 = fmaxf(mx0, __shfl_xor(mx0, 16));
        mx0 = fmaxf(mx0, __shfl_xor(mx0, 32));
        mx1 = fmaxf(mx1, __shfl_xor(mx1, 16));
        mx1 = fmaxf(mx1, __shfl_xor(mx1, 32));
        if (__any((mx0 > m0 + 8.f) || (mx1 > m1 + 8.f))) {   // rare
            const float nm0 = fmaxf(m0, mx0), nm1 = fmaxf(m1, mx1);
            const float sc0 = __expf(m0 - nm0), sc1 = __expf(m1 - nm1);
            m0 = nm0; m1 = nm1;
            l0 *= sc0; l1 *= sc1;
#pragma unroll
            for (int i = 0; i < 16; ++i) {
#pragma unroll
                for (int r = 0; r < 4; ++r) {
                    O0[i][r] *= sc0;
                    O1[i][r] *= sc1;
                }
            }
        }
        float e00[4], e01[4], e10[4], e11[4];
        float rs0 = 0.f, rs1 = 0.f;
#pragma unroll
        for (int r = 0; r < 4; ++r) {
            e00[r] = __expf(S00[r] - m0);
            e01[r] = __expf(S01[r] - m0);
            e10[r] = __expf(S10[r] - m1);
            e11[r] = __expf(S11[r] - m1);
            rs0 += e00[r] + e01[r];
            rs1 += e10[r] + e11[r];
        }
        rs0 += __shfl_xor(rs0, 16);
        rs0 += __shfl_xor(rs0, 32);
        rs1 += __shfl_xor(rs1, 16);
        rs1 += __shfl_xor(rs1, 32);
        l0 += rs0;
        l1 += rs1;

        // ---- pack P(it) lane-locally (overwrites prev AFTER PV consumed it)
        {
            union { int i[4]; hfrag h; } u;
            u.i[0] = pkh(e00[0], e00[1]);
            u.i[1] = pkh(e00[2], e00[3]);
            u.i[2] = pkh(e01[0], e01[1]);
            u.i[3] = pkh(e01[2], e01[3]);
            pb0p = u.h;
            u.i[0] = pkh(e10[0], e10[1]);
            u.i[1] = pkh(e10[2], e10[3]);
            u.i[2] = pkh(e11[0], e11[1]);
            u.i[3] = pkh(e11[2], e11[3]);
            pb1p = u.h;
        }

        __builtin_amdgcn_s_barrier();      // V((it-1)&1) reads done
        __builtin_amdgcn_sched_barrier(0);
        STAGEV((it + 1) & 31, (it + 1) & 1);               // late V prefetch
        __builtin_amdgcn_sched_barrier(0);
    }

    // ---- drain wrapped stages, then final PV(31)
    asm volatile("s_waitcnt vmcnt(0)" ::: "memory");
    __builtin_amdgcn_s_barrier();
    PV(1);                                                 // it=31 -> V buf 1

    // ---- epilogue: kh merge via fp16 LDS overlay, write pO/pML ----
    __syncthreads();
    _Float16* sE = smem;               // [128 row][256 col] fp16, col XOR-swizzled
    const int r0 = qg * 32 + l16;      // this lane's q-rows (0..127)
    const int r1 = r0 + 16;
    const int rsw0 = (r0 & 7) << 3;
    const int rsw1 = (r1 & 7) << 3;
    if (kh == 1) {
        const float inv0 = 1.f / l0, inv1 = 1.f / l1;
#pragma unroll
        for (int ct = 0; ct < 16; ++ct)
#pragma unroll
            for (int r = 0; r < 4; ++r) {
                const int col = ct * 16 + lg * 4 + r;
                sE[r0 * 256 + (col ^ rsw0)] = (_Float16)(O0[ct][r] * inv0);
                sE[r1 * 256 + (col ^ rsw1)] = (_Float16)(O1[ct][r] * inv1);
            }
        if (lg == 0) {
            ((float2*)sml)[r0] = make_float2(m0, l0);
            ((float2*)sml)[r1] = make_float2(m1, l1);
        }
    }
    __syncthreads();
    const size_t mlbase = (size_t)(ksel * 4 + b) * 4096 + n0;
    if (kh == 0) {
        const float2 pml0 = ((const float2*)sml)[r0];
        const float2 pml1 = ((const float2*)sml)[r1];
        const float M0 = fmaxf(m0, pml0.x), M1 = fmaxf(m1, pml1.x);
        const float a0 = __expf(m0 - M0), c0 = __expf(pml0.x - M0);
        const float a1 = __expf(m1 - M1), c1 = __expf(pml1.x - M1);
        const float nl0 = a0 * l0 + c0 * pml0.y;
        const float nl1 = a1 * l1 + c1 * pml1.y;
        const float wa0 = a0 / nl0, wb0 = c0 * pml0.y / nl0;
        const float wa1 = a1 / nl1, wb1 = c1 * pml1.y / nl1;
        if (lg == 0) {
            ((float2*)pML)[mlbase + r0] = make_float2(M0, nl0);
            ((float2*)pML)[mlbase + r1] = make_float2(M1, nl1);
        }
#pragma unroll
        for (int ct = 0; ct < 16; ++ct)
#pragma unroll
            for (int r = 0; r < 4; ++r) {
                const int col = ct * 16 + lg * 4 + r;
                const int i0 = r0 * 256 + (col ^ rsw0);
                const int i1 = r1 * 256 + (col ^ rsw1);
                const float v0 = (float)sE[i0];
                const float v1 = (float)sE[i1];
                sE[i0] = (_Float16)(wa0 * O0[ct][r] + wb0 * v0);
                sE[i1] = (_Float16)(wa1 * O1[ct][r] + wb1 * v1);
            }
    }
    __syncthreads();
    // ---- cooperative coalesced 16B store of the 64KB tile (unswizzle)
    const size_t obase = ((size_t)(ksel * 4 + b) * 4096 + n0) * 256;
#pragma unroll
    for (int i = 0; i < 8; ++i) {
        const int idx = i * 512 + t;            // 0..4095
        const int px = idx >> 5;                // 0..127
        const int cg = idx & 31;                // col-group of 8
        *(us8*)&pO[obase + (size_t)px * 256 + cg * 8] =
            *(const us8*)&sE[px * 256 + (cg ^ (px & 7)) * 8];
    }
}

// ---------------------------------------------------------------------------
// Kernel 4: cross-block flash merge of the two key-halves + BN stats via
// device atomics (kstats2 fused).  512 blocks x 256 threads; block = 32 rows.
// ---------------------------------------------------------------------------
__global__ __launch_bounds__(256) void kmerge(const _Float16* __restrict__ pO,
                                              const float* __restrict__ pML,
                                              _Float16* __restrict__ wbuf,
                                              float* __restrict__ stats) {
    __shared__ float sacc[1024];    // [4 rowloc][256 co]
    __shared__ float sacc2[1024];
    const int t = threadIdx.x;
    const int rowloc = t >> 5;          // 0..7
    const int co8 = (t & 31) * 8;
    float s[8], s2[8];
#pragma unroll
    for (int j = 0; j < 8; ++j) { s[j] = 0.f; s2[j] = 0.f; }
#pragma unroll 2
    for (int i = 0; i < 4; ++i) {
        const int g = blockIdx.x * 32 + i * 8 + rowloc;     // 0..16383
        const float2 ml0 = ((const float2*)pML)[g];
        const float2 ml1 = ((const float2*)pML)[16384 + g];
        const float M = fmaxf(ml0.x, ml1.x);
        const float a = __expf(ml0.x - M) * ml0.y;
        const float c = __expf(ml1.x - M) * ml1.y;
        const float inv = 1.f / (a + c);
        const float wa = a * inv, wc = c * inv;
        hfrag o0 = *(const hfrag*)&pO[(size_t)g * 256 + co8];
        hfrag o1 = *(const hfrag*)&pO[(size_t)(16384 + g) * 256 + co8];
        hfrag w;
#pragma unroll
        for (int j = 0; j < 8; ++j) {
            const float v = wa * (float)o0[j] + wc * (float)o1[j];
            w[j] = (_Float16)v;
            s[j] += v;
            s2[j] += v * v;
        }
        *(hfrag*)&wbuf[(size_t)g * 256 + co8] = w;
    }
    // reduce 8 rowloc groups into 4 (pairwise in registers via LDS round)
#pragma unroll
    for (int j = 0; j < 8; ++j) {
        if (rowloc < 4) {
            sacc[rowloc * 256 + co8 + j] = s[j];
            sacc2[rowloc * 256 + co8 + j] = s2[j];
        }
    }
    __syncthreads();
    if (rowloc >= 4) {
#pragma unroll
        for (int j = 0; j < 8; ++j) {
            atomicAdd(&sacc[(rowloc - 4) * 256 + co8 + j], s[j]);
            atomicAdd(&sacc2[(rowloc - 4) * 256 + co8 + j], s2[j]);
        }
    }
    __syncthreads();
    {
        float p = 0.f, p2 = 0.f;
#pragma unroll
        for (int rl = 0; rl < 4; ++rl) {
            p  += sacc[rl * 256 + t];
            p2 += sacc2[rl * 256 + t];
        }
        atomicAdd(&stats[t], p);
        atomicAdd(&stats[256 + t], p2);
    }
}

// ---------------------------------------------------------------------------
// Kernel 5: apply BN + transpose [b][n][co] -> out[b][co][n] fp32.
// 512 blocks x 256 threads; block = 32 pixels.
// ---------------------------------------------------------------------------
__global__ __launch_bounds__(256) void kapply(const _Float16* __restrict__ w,
                                              const float* __restrict__ stats,
                                              const float* __restrict__ gamma,
                                              const float* __restrict__ beta,
                                              float* __restrict__ out) {
    __shared__ _Float16 sw[32 * 260];           // 32 rows, pad 256->260
    __shared__ float sscale[256];
    __shared__ float sshift[256];
    const int t = threadIdx.x;
    const int b = blockIdx.x >> 7;
    const int n0 = (blockIdx.x & 127) << 5;     // 32-pixel tile
    const _Float16* wb = w + ((size_t)b * 4096 + n0) * 256;
#pragma unroll
    for (int i = 0; i < 8; ++i) {
        const int chunk = i * 256 + t;          // 0..2047 chunks of 4
        const int p = chunk >> 6;
        const int cq = chunk & 63;
        *(us4*)&sw[p * 260 + cq * 4] = *(const us4*)&wb[p * 256 + cq * 4];
    }
    {
        const float mean = stats[t] * (1.f / 16384.f);
        const float var = stats[256 + t] * (1.f / 16384.f) - mean * mean;
        const float inv = rsqrtf(var + 1e-5f);
        const float sc = gamma[t] * inv;
        sscale[t] = sc;
        sshift[t] = beta[t] - mean * sc;
    }
    __syncthreads();
    const int p = t & 31;
    const int cg = t >> 5;                      // 0..7
    float* ob = out + (size_t)b * 256 * 4096 + n0;
#pragma unroll 4
    for (int i = 0; i < 32; ++i) {
        const int co = i * 8 + cg;
        const float v = (float)sw[p * 260 + co];
        ob[(size_t)co * 4096 + p] = v * sscale[co] + sshift[co];
    }
}

// ---------------------------------------------------------------------------
extern "C" void kernel_launch(void* const* d_in, const int* in_sizes, int n_in,
                              void* d_out, int out_size, void* d_ws, size_t ws_size,
                              hipStream_t stream) {
    const float* x     = (const float*)d_in[0];
    const float* Wq    = (const float*)d_in[1];
    const float* bq    = (const float*)d_in[2];
    const float* Wk    = (const float*)d_in[3];
    const float* bk    = (const float*)d_in[4];
    const float* Wv    = (const float*)d_in[5];
    const float* bv    = (const float*)d_in[6];
    const float* gamma = (const float*)d_in[7];
    const float* beta  = (const float*)d_in[8];
    float* out = (float*)d_out;

    char* ws = (char*)d_ws;
    // lifetimes: Wh/ball [kprep->kproj]; pML aliases Wh [kattn->kmerge];
    // Qb/Kb [kproj->kattn]; wbuf aliases Qb+Kb [kmerge->kapply].
    _Float16* Wh    = (_Float16*)(ws + 0x0);        // 256 KB
    float*    pML   = (float*)(ws + 0x0);           // 256 KB (2x4x4096 float2)
    float*    ball  = (float*)(ws + 0x40000);       // 2 KB
    float*    stats = (float*)(ws + 0x40800);       // 2 KB
    _Float16* Qb    = (_Float16*)(ws + 0x100000);   // 4 MB
    _Float16* Kb    = (_Float16*)(ws + 0x500000);   // 4 MB
    _Float16* wbuf  = (_Float16*)(ws + 0x100000);   // 8 MB over Qb+Kb
    _Float16* Vb    = (_Float16*)(ws + 0x900000);   // 8 MB
    _Float16* pO    = (_Float16*)(ws + 0x1100000);  // 16 MB (2x4x4096x256 fp16)
    if (ws_size < 0x2100000) return;  // 33 MB scratch (verified available)

    kprep<<<512, 256, 0, stream>>>(Wq, Wk, Wv, bq, bk, bv, Wh, ball, stats);
    kproj<<<256, 256, 0, stream>>>(x, Wh, ball, Qb, Kb, Vb);
    kattn<<<256, 512, 0, stream>>>(Qb, Kb, Vb, pO, pML);
    kmerge<<<512, 256, 0, stream>>>(pO, pML, wbuf, stats);
    kapply<<<512, 256, 0, stream>>>(wbuf, stats, gamma, beta, out);
}

// Round 20
// 135.023 us; speedup vs baseline: 1.1240x; 1.0661x over previous
//
#include <hip/hip_runtime.h>
#include <hip/hip_bf16.h>

typedef __attribute__((ext_vector_type(8))) _Float16 hfrag;
typedef __attribute__((ext_vector_type(4))) float ffrag;
typedef __attribute__((ext_vector_type(8))) unsigned short us8;
typedef __attribute__((ext_vector_type(4))) unsigned short us4;

#define DEVINL static __device__ __forceinline__
#define MFMAH(a, b, c)  __builtin_amdgcn_mfma_f32_16x16x32_f16((a), (b), (c), 0, 0, 0)

// async global->LDS, 16B per lane; LDS dest = wave-uniform base + lane*16
DEVINL void gload_lds16(const _Float16* g, _Float16* l) {
    __builtin_amdgcn_global_load_lds(
        (const __attribute__((address_space(1))) unsigned int*)g,
        (__attribute__((address_space(3))) unsigned int*)l, 16, 0, 0);
}

DEVINL int pkh(float a, float b) {       // pack 2 f32 -> fp16x2 dword
    typedef __attribute__((ext_vector_type(2))) __fp16 fp16x2;
    fp16x2 t = __builtin_amdgcn_cvt_pkrtz(a, b);
    union { fp16x2 h; int i; } u; u.h = t; return u.i;
}

// V key-permutation within 32-element groups (split-k fragment mapping fix).
DEVINL int permV(int p) {
    return (p & 35) | ((p & 8) << 1) | ((p & 4) << 1) | ((p & 16) >> 2);
}

// ---------------------------------------------------------------------------
// Kernel 1: pack weights to fp16 [512][256], gather biases.
// ---------------------------------------------------------------------------
__global__ void kprep(const float* __restrict__ Wq, const float* __restrict__ Wk,
                      const float* __restrict__ Wv, const float* __restrict__ bq,
                      const float* __restrict__ bk, const float* __restrict__ bv,
                      _Float16* __restrict__ Wh, float* __restrict__ ball) {
    int t = blockIdx.x * 256 + threadIdx.x;      // 512*256 threads
    int o = t >> 8, c = t & 255;
    float v = (o < 128) ? Wq[o * 256 + c]
            : (o < 256) ? Wk[(o - 128) * 256 + c]
                        : Wv[(o - 256) * 256 + c];
    Wh[t] = (_Float16)v;
    if (c == 0) {
        ball[o] = (o < 128) ? bq[o] : (o < 256) ? bk[o - 128] : bv[o - 256];
    }
}

// ---------------------------------------------------------------------------
// Kernel 2: 1x1 conv projections via fp16 MFMA.
// Q,K written [b][n][128] fp16; V written [b][co][n] fp16 (operand swap),
// with key-index permV within 32-pixel groups.
// ---------------------------------------------------------------------------
__global__ __launch_bounds__(256) void kproj(const float* __restrict__ x,
                                             const _Float16* __restrict__ Wh,
                                             const float* __restrict__ ball,
                                             _Float16* __restrict__ Qb,
                                             _Float16* __restrict__ Kb,
                                             _Float16* __restrict__ Vb) {
    __shared__ _Float16 sX[64 * 256];             // [pixel][ch], XOR-swizzled, 32KB
    const int t = threadIdx.x;
    const int lane = t & 63;
    const int wv = t >> 6;
    const int l16 = lane & 15;
    const int lg = lane >> 4;
    const int b = blockIdx.x >> 6;
    const int n0 = (blockIdx.x & 63) << 6;
    const float* xb = x + (size_t)b * 256 * 4096 + n0;

    // stage x^T tile: thread = pixel p (=lane), channel group by wave
    const int p = lane;
#pragma unroll
    for (int ci = 0; ci < 8; ++ci) {
        const int c0 = ci * 32 + (wv << 3);
        __align__(16) _Float16 th[8];
#pragma unroll
        for (int j = 0; j < 8; ++j) th[j] = (_Float16)xb[(size_t)(c0 + j) * 4096 + p];
        *(us8*)&sX[p * 256 + (c0 ^ ((p & 7) << 3))] = *(const us8*)th;
    }
    __syncthreads();

    ffrag accQK[16];  // D[pixel 16*wv+..][o=16ct+l16], o in 0..255 (Q,K)
    ffrag accV[16];   // D[o=256+64*wv+16mt+..][pixel 16*c2+l16]
#pragma unroll
    for (int i = 0; i < 16; ++i) {
        accQK[i] = ffrag{0.f, 0.f, 0.f, 0.f};
        accV[i]  = ffrag{0.f, 0.f, 0.f, 0.f};
    }
    const int rowx = 16 * wv + l16;
#pragma unroll
    for (int step = 0; step < 8; ++step) {
        const int cb = step * 32 + (lg << 3);
        hfrag ax = *(const hfrag*)&sX[rowx * 256 + (cb ^ ((rowx & 7) << 3))];
#pragma unroll
        for (int ct = 0; ct < 16; ++ct) {
            const int o = ct * 16 + l16;
            hfrag bw = *(const hfrag*)&Wh[o * 256 + cb];
            accQK[ct] = MFMAH(ax, bw, accQK[ct]);
        }
        hfrag bx[4];
#pragma unroll
        for (int c2 = 0; c2 < 4; ++c2) {
            const int px = c2 * 16 + l16;
            bx[c2] = *(const hfrag*)&sX[px * 256 + (cb ^ ((px & 7) << 3))];
        }
#pragma unroll
        for (int mt = 0; mt < 4; ++mt) {
            const int o = 256 + 64 * wv + 16 * mt + l16;
            hfrag aw = *(const hfrag*)&Wh[o * 256 + cb];
#pragma unroll
            for (int c2 = 0; c2 < 4; ++c2)
                accV[mt * 4 + c2] = MFMAH(aw, bx[c2], accV[mt * 4 + c2]);
        }
    }

    // epilogue: +bias, fp16, store
#pragma unroll
    for (int ct = 0; ct < 16; ++ct) {
        const int o = ct * 16 + l16;
        const float bias = ball[o];
        _Float16* dst = (o < 128) ? Qb : Kb;
        const int oo = o & 127;
#pragma unroll
        for (int r = 0; r < 4; ++r) {
            const int px = 16 * wv + (lg << 2) + r;
            dst[((size_t)b * 4096 + n0 + px) * 128 + oo] = (_Float16)(accQK[ct][r] + bias);
        }
    }
#pragma unroll
    for (int mt = 0; mt < 4; ++mt) {
#pragma unroll
        for (int r = 0; r < 4; ++r) {
            const int o = 64 * wv + 16 * mt + (lg << 2) + r;
            const float bias = ball[256 + o];
#pragma unroll
            for (int c2 = 0; c2 < 4; ++c2) {
                const int px = c2 * 16 + l16;
                Vb[((size_t)b * 256 + o) * 4096 + n0 + permV(px)] =
                    (_Float16)(accV[mt * 4 + c2][r] + bias);
            }
        }
    }
}

// ---------------------------------------------------------------------------
// Kernel 3: fused flash attention (round-15 best: ~80 us).
// KEY-SPLIT, SWAPPED QK^T, 32q/wave, full K/V dbuf + deferred-PV + setprio.
// 256 blocks x 512 threads = 4 batches x 32 q-tiles(128 rows) x 2 key-halves.
// ---------------------------------------------------------------------------
__global__ __launch_bounds__(512, 2) void kattn(const _Float16* __restrict__ Qb,
                                                const _Float16* __restrict__ Kb,
                                                const _Float16* __restrict__ Vb,
                                                _Float16* __restrict__ pO,
                                                float* __restrict__ pML) {
    __shared__ __align__(16) _Float16 smem[49664];  // 97 KB
    // K0 @0 | K1 @8192 | V0 @16384 | V1 @32768 | sml @49152
    float* sml = (float*)(smem + 49152);            // [128] float2 (1KB)

    const int t = threadIdx.x;
    const int lane = t & 63;
    const int wv = t >> 6;        // 0..7
    const int qg = wv & 3;        // 32-row query group (0..3)
    const int kh = wv >> 2;       // 32-key half (0..1)
    const int l16 = lane & 15;
    const int lg = lane >> 4;

    const int blk = blockIdx.x;
    const int x8 = blk & 7;
    const int b = x8 >> 1;                          // batch per XCD pair
    const int ksel = x8 & 1;                        // key half per XCD
    const int qt5 = blk >> 3;                       // 0..31
    const int n0 = qt5 << 7;                        // 128 q-rows per block
    const int kb = ksel << 11;                      // key base (0 or 2048)

    const _Float16* Kg = Kb + (size_t)b * 4096 * 128;
    const _Float16* Vg = Vb + (size_t)b * 256 * 4096;

    // ---- Q fragments for both q-tiles (rows qg*32+l16 and qg*32+16+l16)
    hfrag aq0[4], aq1[4];
    {
        const size_t gq0 = ((size_t)b * 4096 + n0 + qg * 32 + l16) * 128;
        const size_t gq1 = gq0 + 16 * 128;
#pragma unroll
        for (int st = 0; st < 4; ++st) {
            aq0[st] = *(const hfrag*)&Qb[gq0 + st * 32 + lg * 8];
            aq1[st] = *(const hfrag*)&Qb[gq1 + st * 32 + lg * 8];
        }
    }

    float m0 = -3e38f, l0 = 0.f;      // q-row r0 = qg*32 + l16
    float m1 = -3e38f, l1 = 0.f;      // q-row r1 = r0 + 16
    ffrag O0[16], O1[16];             // O^T[co = ct*16+lg*4+r][q]
#pragma unroll
    for (int i = 0; i < 16; ++i) {
        O0[i] = ffrag{0.f, 0.f, 0.f, 0.f};
        O1[i] = ffrag{0.f, 0.f, 0.f, 0.f};
    }
    hfrag pb0p, pb1p;                 // P fragments of iter i-1 (deferred PV)

    // staging lane constants
    const int krow_in = lane >> 4;              // K: row-in-chunk (0..3)
    const int kcol = lane & 15;                 // K: col chunk index
    const int vrow_in = lane >> 3;              // V: row-in-chunk (0..7)
    const int vcol = lane & 7;                  // V: col chunk index

    // stage K tile `it` into K buf bsel: 2 loads/wave
    auto STAGEK = [&](int it, int bsel) {
        const int k0 = kb + (it << 6);
        _Float16* sK = smem + (bsel << 13);
#pragma unroll
        for (int j = 0; j < 2; ++j) {
            const int c = 2 * wv + j;           // 0..15
            const int row = 4 * c + krow_in;
            gload_lds16(Kg + (size_t)(k0 + row) * 128 + ((kcol ^ (row & 7)) << 3),
                        sK + c * 512);
        }
    };
    // stage V tile `it` into V buf bsel: 4 loads/wave
    auto STAGEV = [&](int it, int bsel) {
        const int k0 = kb + (it << 6);
        _Float16* sV = smem + 16384 + (bsel << 14);
#pragma unroll
        for (int j = 0; j < 4; ++j) {
            const int cv = 4 * wv + j;          // 0..31
            const int co = 8 * cv + vrow_in;
            gload_lds16(Vg + (size_t)co * 4096 + k0 + ((vcol ^ (co & 7)) << 3),
                        sV + cv * 512);
        }
    };

    // deferred PV: O += V(it-1) P(it-1)^T  (reads V buf (it-1)&1)
    auto PV = [&](int bsel) {
        const _Float16* sV = smem + 16384 + (bsel << 14);
#pragma unroll
        for (int ct = 0; ct < 16; ++ct) {
            const int co = ct * 16 + l16;
            hfrag av = *(const hfrag*)&sV[co * 64 + ((kh * 32 + lg * 8) ^ ((co & 7) << 3))];
            O0[ct] = MFMAH(av, pb0p, O0[ct]);
            O1[ct] = MFMAH(av, pb1p, O1[ct]);
        }
    };

    // ---- prologue: stage K(0), V(0) into buf0
    STAGEK(0, 0);
    STAGEV(0, 0);
    __builtin_amdgcn_sched_barrier(0);

#pragma unroll 1
    for (int it = 0; it < 32; ++it) {
        asm volatile("s_waitcnt vmcnt(4)" ::: "memory");   // K(it) [+V(it-1)] landed
        __builtin_amdgcn_s_barrier();
        __builtin_amdgcn_sched_barrier(0);
        STAGEK((it + 1) & 31, (it + 1) & 1);               // early K prefetch
        __builtin_amdgcn_sched_barrier(0);

        const _Float16* sK = smem + ((it & 1) << 13);

        __builtin_amdgcn_s_setprio(1);
        // ---- S^T = K Q^T, 2 q-tiles share each K fragment
        ffrag S00 = ffrag{0.f,0.f,0.f,0.f}, S01 = ffrag{0.f,0.f,0.f,0.f};
        ffrag S10 = ffrag{0.f,0.f,0.f,0.f}, S11 = ffrag{0.f,0.f,0.f,0.f};
#pragma unroll
        for (int kt = 0; kt < 2; ++kt) {
            const int rowk = kh * 32 + kt * 16 + l16;
            const int swz = (rowk & 7) << 3;
#pragma unroll
            for (int st = 0; st < 4; ++st) {
                hfrag ak = *(const hfrag*)&sK[rowk * 128 + ((st * 32 + lg * 8) ^ swz)];
                if (kt == 0) {
                    S00 = MFMAH(ak, aq0[st], S00);
                    S10 = MFMAH(ak, aq1[st], S10);
                } else {
                    S01 = MFMAH(ak, aq0[st], S01);
                    S11 = MFMAH(ak, aq1[st], S11);
                }
            }
        }
        // ---- deferred PV(it-1): MFMA cluster independent of softmax(it)
        if (it > 0) PV((it - 1) & 1);
        __builtin_amdgcn_s_setprio(0);

        // ---- online softmax per q-row (2 rows/lane), defer-max THR=8
        float mx0 = fmaxf(fmaxf(fmaxf(S00[0], S00[1]), fmaxf(S00[2], S00[3])),
                          fmaxf(fmaxf(S01[0], S01[1]), fmaxf(S01[2], S01[3])));
        float mx1 = fmaxf(fmaxf(fmaxf(S10[0], S10[1]), fmaxf(S10[2], S10[3])),
                          fmaxf(fmaxf(S11[0], S11[1]), fmaxf(S11[2], S11[3])));
        mx0 = fmaxf(mx0, __shfl_xor(mx0, 16));
        mx0 = fmaxf(mx0, __shfl_xor(mx0, 32));
        mx1 = fmaxf(mx1, __shfl_xor(mx1, 16));
        mx1 = fmaxf(mx1, __shfl_xor(mx1, 32));
        if (__any((mx0 > m0 + 8.f) || (mx1 > m1 + 8.f))) {   // rare
            const float nm0 = fmaxf(m0, mx0), nm1 = fmaxf(m1, mx1);
            const float sc0 = __expf(m0 - nm0), sc1 = __expf(m1 - nm1);
            m0 = nm0; m1 = nm1;
            l0 *= sc0; l1 *= sc1;
#pragma unroll
            for (int i = 0; i < 16; ++i) {
#pragma unroll
                for (int r = 0; r < 4; ++r) {
                    O0[i][r] *= sc0;
                    O1[i][r] *= sc1;
                }
            }
        }
        float e00[4], e01[4], e10[4], e11[4];
        float rs0 = 0.f, rs1 = 0.f;
#pragma unroll
        for (int r = 0; r < 4; ++r) {
            e00[r] = __expf(S00[r] - m0);
            e01[r] = __expf(S01[r] - m0);
            e10[r] = __expf(S10[r] - m1);
            e11[r] = __expf(S11[r] - m1);
            rs0 += e00[r] + e01[r];
            rs1 += e10[r] + e11[r];
        }
        rs0 += __shfl_xor(rs0, 16);
        rs0 += __shfl_xor(rs0, 32);
        rs1 += __shfl_xor(rs1, 16);
        rs1 += __shfl_xor(rs1, 32);
        l0 += rs0;
        l1 += rs1;

        // ---- pack P(it) lane-locally (overwrites prev AFTER PV consumed it)
        {
            union { int i[4]; hfrag h; } u;
            u.i[0] = pkh(e00[0], e00[1]);
            u.i[1] = pkh(e00[2], e00[3]);
            u.i[2] = pkh(e01[0], e01[1]);
            u.i[3] = pkh(e01[2], e01[3]);
            pb0p = u.h;
            u.i[0] = pkh(e10[0], e10[1]);
            u.i[1] = pkh(e10[2], e10[3]);
            u.i[2] = pkh(e11[0], e11[1]);
            u.i[3] = pkh(e11[2], e11[3]);
            pb1p = u.h;
        }

        __builtin_amdgcn_s_barrier();      // V((it-1)&1) reads done
        __builtin_amdgcn_sched_barrier(0);
        STAGEV((it + 1) & 31, (it + 1) & 1);               // late V prefetch
        __builtin_amdgcn_sched_barrier(0);
    }

    // ---- drain wrapped stages, then final PV(31)
    asm volatile("s_waitcnt vmcnt(0)" ::: "memory");
    __builtin_amdgcn_s_barrier();
    PV(1);                                                 // it=31 -> V buf 1

    // ---- epilogue: kh merge via fp16 LDS overlay, write pO/pML ----
    __syncthreads();
    _Float16* sE = smem;               // [128 row][256 col] fp16, col XOR-swizzled
    const int r0 = qg * 32 + l16;      // this lane's q-rows (0..127)
    const int r1 = r0 + 16;
    const int rsw0 = (r0 & 7) << 3;
    const int rsw1 = (r1 & 7) << 3;
    if (kh == 1) {
        const float inv0 = 1.f / l0, inv1 = 1.f / l1;
#pragma unroll
        for (int ct = 0; ct < 16; ++ct)
#pragma unroll
            for (int r = 0; r < 4; ++r) {
                const int col = ct * 16 + lg * 4 + r;
                sE[r0 * 256 + (col ^ rsw0)] = (_Float16)(O0[ct][r] * inv0);
                sE[r1 * 256 + (col ^ rsw1)] = (_Float16)(O1[ct][r] * inv1);
            }
        if (lg == 0) {
            ((float2*)sml)[r0] = make_float2(m0, l0);
            ((float2*)sml)[r1] = make_float2(m1, l1);
        }
    }
    __syncthreads();
    const size_t mlbase = (size_t)(ksel * 4 + b) * 4096 + n0;
    if (kh == 0) {
        const float2 pml0 = ((const float2*)sml)[r0];
        const float2 pml1 = ((const float2*)sml)[r1];
        const float M0 = fmaxf(m0, pml0.x), M1 = fmaxf(m1, pml1.x);
        const float a0 = __expf(m0 - M0), c0 = __expf(pml0.x - M0);
        const float a1 = __expf(m1 - M1), c1 = __expf(pml1.x - M1);
        const float nl0 = a0 * l0 + c0 * pml0.y;
        const float nl1 = a1 * l1 + c1 * pml1.y;
        const float wa0 = a0 / nl0, wb0 = c0 * pml0.y / nl0;
        const float wa1 = a1 / nl1, wb1 = c1 * pml1.y / nl1;
        if (lg == 0) {
            ((float2*)pML)[mlbase + r0] = make_float2(M0, nl0);
            ((float2*)pML)[mlbase + r1] = make_float2(M1, nl1);
        }
#pragma unroll
        for (int ct = 0; ct < 16; ++ct)
#pragma unroll
            for (int r = 0; r < 4; ++r) {
                const int col = ct * 16 + lg * 4 + r;
                const int i0 = r0 * 256 + (col ^ rsw0);
                const int i1 = r1 * 256 + (col ^ rsw1);
                const float v0 = (float)sE[i0];
                const float v1 = (float)sE[i1];
                sE[i0] = (_Float16)(wa0 * O0[ct][r] + wb0 * v0);
                sE[i1] = (_Float16)(wa1 * O1[ct][r] + wb1 * v1);
            }
    }
    __syncthreads();
    // ---- cooperative coalesced 16B store of the 64KB tile (unswizzle)
    const size_t obase = ((size_t)(ksel * 4 + b) * 4096 + n0) * 256;
#pragma unroll
    for (int i = 0; i < 8; ++i) {
        const int idx = i * 512 + t;            // 0..4095
        const int px = idx >> 5;                // 0..127
        const int cg = idx & 31;                // col-group of 8
        *(us8*)&pO[obase + (size_t)px * 256 + cg * 8] =
            *(const us8*)&sE[px * 256 + (cg ^ (px & 7)) * 8];
    }
}

// ---------------------------------------------------------------------------
// Kernel 4: cross-block flash merge of the two key-halves + BN partial sums.
// 256 blocks x 256 threads; block = 64 rows.  Deterministic.
// ---------------------------------------------------------------------------
__global__ __launch_bounds__(256) void kmerge(const _Float16* __restrict__ pO,
                                              const float* __restrict__ pML,
                                              _Float16* __restrict__ wbuf,
                                              float* __restrict__ part) {
    __shared__ float sacc[2048];    // [8 rowloc][256 co]
    __shared__ float sacc2[2048];
    const int t = threadIdx.x;
    const int rowloc = t >> 5;          // 0..7
    const int co8 = (t & 31) * 8;
    float s[8], s2[8];
#pragma unroll
    for (int j = 0; j < 8; ++j) { s[j] = 0.f; s2[j] = 0.f; }
#pragma unroll 2
    for (int i = 0; i < 8; ++i) {
        const int g = blockIdx.x * 64 + i * 8 + rowloc;     // 0..16383
        const float2 ml0 = ((const float2*)pML)[g];
        const float2 ml1 = ((const float2*)pML)[16384 + g];
        const float M = fmaxf(ml0.x, ml1.x);
        const float a = __expf(ml0.x - M) * ml0.y;
        const float c = __expf(ml1.x - M) * ml1.y;
        const float inv = 1.f / (a + c);
        const float wa = a * inv, wc = c * inv;
        hfrag o0 = *(const hfrag*)&pO[(size_t)g * 256 + co8];
        hfrag o1 = *(const hfrag*)&pO[(size_t)(16384 + g) * 256 + co8];
        hfrag w;
#pragma unroll
        for (int j = 0; j < 8; ++j) {
            const float v = wa * (float)o0[j] + wc * (float)o1[j];
            w[j] = (_Float16)v;
            s[j] += v;
            s2[j] += v * v;
        }
        *(hfrag*)&wbuf[(size_t)g * 256 + co8] = w;
    }
#pragma unroll
    for (int j = 0; j < 8; ++j) {
        sacc[rowloc * 256 + co8 + j] = s[j];
        sacc2[rowloc * 256 + co8 + j] = s2[j];
    }
    __syncthreads();
    float p = 0.f, p2 = 0.f;
#pragma unroll
    for (int rl = 0; rl < 8; ++rl) {
        p  += sacc[rl * 256 + t];
        p2 += sacc2[rl * 256 + t];
    }
    part[blockIdx.x * 512 + t] = p;
    part[blockIdx.x * 512 + 256 + t] = p2;
}

// Kernel 4b: reduce partials -> stats[512]. 512 blocks x 64 lanes,
// deterministic fixed-tree shuffle reduce over 256 partial blocks.
__global__ void kstats2(const float* __restrict__ partial, float* __restrict__ stats) {
    const int ch = blockIdx.x;        // 0..511
    const int j = threadIdx.x;        // 0..63
    float s = 0.f;
#pragma unroll
    for (int i = 0; i < 4; ++i)
        s += partial[(size_t)(j + 64 * i) * 512 + ch];
    s += __shfl_xor(s, 1);
    s += __shfl_xor(s, 2);
    s += __shfl_xor(s, 4);
    s += __shfl_xor(s, 8);
    s += __shfl_xor(s, 16);
    s += __shfl_xor(s, 32);
    if (j == 0) stats[ch] = s;
}

// ---------------------------------------------------------------------------
// Kernel 5: apply BN + transpose [b][n][co] -> out[b][co][n] fp32.
// ---------------------------------------------------------------------------
__global__ __launch_bounds__(256) void kapply(const _Float16* __restrict__ w,
                                              const float* __restrict__ stats,
                                              const float* __restrict__ gamma,
                                              const float* __restrict__ beta,
                                              float* __restrict__ out) {
    __shared__ _Float16 sw[64 * 260];           // 64 rows, pad 256->260
    __shared__ float sscale[256];
    __shared__ float sshift[256];
    const int t = threadIdx.x;
    const int b = blockIdx.x >> 6;
    const int n0 = (blockIdx.x & 63) << 6;
    const _Float16* wb = w + ((size_t)b * 4096 + n0) * 256;
#pragma unroll
    for (int i = 0; i < 16; ++i) {
        const int chunk = i * 256 + t;
        const int p = chunk >> 6;
        const int cq = chunk & 63;
        *(us4*)&sw[p * 260 + cq * 4] = *(const us4*)&wb[p * 256 + cq * 4];
    }
    {
        const float mean = stats[t] * (1.f / 16384.f);
        const float var = stats[256 + t] * (1.f / 16384.f) - mean * mean;
        const float inv = rsqrtf(var + 1e-5f);
        const float sc = gamma[t] * inv;
        sscale[t] = sc;
        sshift[t] = beta[t] - mean * sc;
    }
    __syncthreads();
    const int p = t & 63;
    const int cg = t >> 6;
    float* ob = out + (size_t)b * 256 * 4096 + n0;
#pragma unroll 4
    for (int i = 0; i < 64; ++i) {
        const int co = i * 4 + cg;
        const float v = (float)sw[p * 260 + co];
        ob[(size_t)co * 4096 + p] = v * sscale[co] + sshift[co];
    }
}

// ---------------------------------------------------------------------------
extern "C" void kernel_launch(void* const* d_in, const int* in_sizes, int n_in,
                              void* d_out, int out_size, void* d_ws, size_t ws_size,
                              hipStream_t stream) {
    const float* x     = (const float*)d_in[0];
    const float* Wq    = (const float*)d_in[1];
    const float* bq    = (const float*)d_in[2];
    const float* Wk    = (const float*)d_in[3];
    const float* bk    = (const float*)d_in[4];
    const float* Wv    = (const float*)d_in[5];
    const float* bv    = (const float*)d_in[6];
    const float* gamma = (const float*)d_in[7];
    const float* beta  = (const float*)d_in[8];
    float* out = (float*)d_out;

    char* ws = (char*)d_ws;
    // lifetimes: Wh/ball [kprep->kproj]; pML aliases Wh [kattn->kmerge];
    // Qb/Kb [kproj->kattn]; wbuf aliases Qb+Kb [kmerge->kapply].
    _Float16* Wh    = (_Float16*)(ws + 0x0);        // 256 KB
    float*    pML   = (float*)(ws + 0x0);           // 256 KB (2x4x4096 float2)
    float*    ball  = (float*)(ws + 0x40000);       // 2 KB
    float*    stats = (float*)(ws + 0x40800);       // 2 KB
    float*    part  = (float*)(ws + 0x41000);       // 512 KB (256 x 512 f32)
    _Float16* Qb    = (_Float16*)(ws + 0x100000);   // 4 MB
    _Float16* Kb    = (_Float16*)(ws + 0x500000);   // 4 MB
    _Float16* wbuf  = (_Float16*)(ws + 0x100000);   // 8 MB over Qb+Kb
    _Float16* Vb    = (_Float16*)(ws + 0x900000);   // 8 MB
    _Float16* pO    = (_Float16*)(ws + 0x1100000);  // 16 MB (2x4x4096x256 fp16)
    if (ws_size < 0x2100000) return;  // 33 MB scratch (verified available)

    kprep<<<512, 256, 0, stream>>>(Wq, Wk, Wv, bq, bk, bv, Wh, ball);
    kproj<<<256, 256, 0, stream>>>(x, Wh, ball, Qb, Kb, Vb);
    kattn<<<256, 512, 0, stream>>>(Qb, Kb, Vb, pO, pML);
    kmerge<<<256, 256, 0, stream>>>(pO, pML, wbuf, part);
    kstats2<<<512, 64, 0, stream>>>(part, stats);
    kapply<<<256, 256, 0, stream>>>(wbuf, stats, gamma, beta, out);
}

// Round 21
// 133.054 us; speedup vs baseline: 1.1406x; 1.0148x over previous
//
#include <hip/hip_runtime.h>
#include <hip/hip_bf16.h>

typedef __attribute__((ext_vector_type(8))) _Float16 hfrag;
typedef __attribute__((ext_vector_type(4))) float ffrag;
typedef __attribute__((ext_vector_type(8))) unsigned short us8;
typedef __attribute__((ext_vector_type(4))) unsigned short us4;

#define DEVINL static __device__ __forceinline__
#define MFMAH(a, b, c)  __builtin_amdgcn_mfma_f32_16x16x32_f16((a), (b), (c), 0, 0, 0)

// async global->LDS, 16B per lane; LDS dest = wave-uniform base + lane*16
DEVINL void gload_lds16(const _Float16* g, _Float16* l) {
    __builtin_amdgcn_global_load_lds(
        (const __attribute__((address_space(1))) unsigned int*)g,
        (__attribute__((address_space(3))) unsigned int*)l, 16, 0, 0);
}

DEVINL int pkh(float a, float b) {       // pack 2 f32 -> fp16x2 dword
    typedef __attribute__((ext_vector_type(2))) __fp16 fp16x2;
    fp16x2 t = __builtin_amdgcn_cvt_pkrtz(a, b);
    union { fp16x2 h; int i; } u; u.h = t; return u.i;
}

// V key-permutation within 32-element groups (split-k fragment mapping fix).
DEVINL int permV(int p) {
    return (p & 35) | ((p & 8) << 1) | ((p & 4) << 1) | ((p & 16) >> 2);
}

// ---------------------------------------------------------------------------
// Kernel 1: pack weights to fp16 [512][256], gather biases.
// ---------------------------------------------------------------------------
__global__ void kprep(const float* __restrict__ Wq, const float* __restrict__ Wk,
                      const float* __restrict__ Wv, const float* __restrict__ bq,
                      const float* __restrict__ bk, const float* __restrict__ bv,
                      _Float16* __restrict__ Wh, float* __restrict__ ball) {
    int t = blockIdx.x * 256 + threadIdx.x;      // 512*256 threads
    int o = t >> 8, c = t & 255;
    float v = (o < 128) ? Wq[o * 256 + c]
            : (o < 256) ? Wk[(o - 128) * 256 + c]
                        : Wv[(o - 256) * 256 + c];
    Wh[t] = (_Float16)v;
    if (c == 0) {
        ball[o] = (o < 128) ? bq[o] : (o < 256) ? bk[o - 128] : bv[o - 256];
    }
}

// ---------------------------------------------------------------------------
// Kernel 2: 1x1 conv projections via fp16 MFMA.
// Q,K written [b][n][128] fp16; V written [b][co][n] fp16 (operand swap),
// with key-index permV within 32-pixel groups.
// ---------------------------------------------------------------------------
__global__ __launch_bounds__(256) void kproj(const float* __restrict__ x,
                                             const _Float16* __restrict__ Wh,
                                             const float* __restrict__ ball,
                                             _Float16* __restrict__ Qb,
                                             _Float16* __restrict__ Kb,
                                             _Float16* __restrict__ Vb) {
    __shared__ _Float16 sX[64 * 256];             // [pixel][ch], XOR-swizzled, 32KB
    const int t = threadIdx.x;
    const int lane = t & 63;
    const int wv = t >> 6;
    const int l16 = lane & 15;
    const int lg = lane >> 4;
    const int b = blockIdx.x >> 6;
    const int n0 = (blockIdx.x & 63) << 6;
    const float* xb = x + (size_t)b * 256 * 4096 + n0;

    // stage x^T tile: thread = pixel p (=lane), channel group by wave
    const int p = lane;
#pragma unroll
    for (int ci = 0; ci < 8; ++ci) {
        const int c0 = ci * 32 + (wv << 3);
        __align__(16) _Float16 th[8];
#pragma unroll
        for (int j = 0; j < 8; ++j) th[j] = (_Float16)xb[(size_t)(c0 + j) * 4096 + p];
        *(us8*)&sX[p * 256 + (c0 ^ ((p & 7) << 3))] = *(const us8*)th;
    }
    __syncthreads();

    ffrag accQK[16];  // D[pixel 16*wv+..][o=16ct+l16], o in 0..255 (Q,K)
    ffrag accV[16];   // D[o=256+64*wv+16mt+..][pixel 16*c2+l16]
#pragma unroll
    for (int i = 0; i < 16; ++i) {
        accQK[i] = ffrag{0.f, 0.f, 0.f, 0.f};
        accV[i]  = ffrag{0.f, 0.f, 0.f, 0.f};
    }
    const int rowx = 16 * wv + l16;
#pragma unroll
    for (int step = 0; step < 8; ++step) {
        const int cb = step * 32 + (lg << 3);
        hfrag ax = *(const hfrag*)&sX[rowx * 256 + (cb ^ ((rowx & 7) << 3))];
#pragma unroll
        for (int ct = 0; ct < 16; ++ct) {
            const int o = ct * 16 + l16;
            hfrag bw = *(const hfrag*)&Wh[o * 256 + cb];
            accQK[ct] = MFMAH(ax, bw, accQK[ct]);
        }
        hfrag bx[4];
#pragma unroll
        for (int c2 = 0; c2 < 4; ++c2) {
            const int px = c2 * 16 + l16;
            bx[c2] = *(const hfrag*)&sX[px * 256 + (cb ^ ((px & 7) << 3))];
        }
#pragma unroll
        for (int mt = 0; mt < 4; ++mt) {
            const int o = 256 + 64 * wv + 16 * mt + l16;
            hfrag aw = *(const hfrag*)&Wh[o * 256 + cb];
#pragma unroll
            for (int c2 = 0; c2 < 4; ++c2)
                accV[mt * 4 + c2] = MFMAH(aw, bx[c2], accV[mt * 4 + c2]);
        }
    }

    // epilogue: +bias, fp16, store
#pragma unroll
    for (int ct = 0; ct < 16; ++ct) {
        const int o = ct * 16 + l16;
        const float bias = ball[o];
        _Float16* dst = (o < 128) ? Qb : Kb;
        const int oo = o & 127;
#pragma unroll
        for (int r = 0; r < 4; ++r) {
            const int px = 16 * wv + (lg << 2) + r;
            dst[((size_t)b * 4096 + n0 + px) * 128 + oo] = (_Float16)(accQK[ct][r] + bias);
        }
    }
#pragma unroll
    for (int mt = 0; mt < 4; ++mt) {
#pragma unroll
        for (int r = 0; r < 4; ++r) {
            const int o = 64 * wv + 16 * mt + (lg << 2) + r;
            const float bias = ball[256 + o];
#pragma unroll
            for (int c2 = 0; c2 < 4; ++c2) {
                const int px = c2 * 16 + l16;
                Vb[((size_t)b * 256 + o) * 4096 + n0 + permV(px)] =
                    (_Float16)(accV[mt * 4 + c2][r] + bias);
            }
        }
    }
}

// ---------------------------------------------------------------------------
// Kernel 3: fused flash attention.  Round-15 body with TRIPLE-BUFFERED V:
// single barrier per iteration (WAR on V buf (it+1)%3 is protected by the
// top-of-iter barrier, since its last reader PV(it-2) ran in iter it-1).
// KEY-SPLIT, SWAPPED QK^T, 32q/wave, K dbuf + V 3buf + deferred-PV + setprio.
// 256 blocks x 512 threads = 4 batches x 32 q-tiles(128 rows) x 2 key-halves.
// LDS 129KB, 1 block/CU, 2 waves/SIMD; waves may skew a full iter body.
// ---------------------------------------------------------------------------
__global__ __launch_bounds__(512, 2) void kattn(const _Float16* __restrict__ Qb,
                                                const _Float16* __restrict__ Kb,
                                                const _Float16* __restrict__ Vb,
                                                _Float16* __restrict__ pO,
                                                float* __restrict__ pML) {
    __shared__ __align__(16) _Float16 smem[66048];  // 129 KB
    // K0 @0 | K1 @8192 | V0 @16384 | V1 @32768 | V2 @49152 | sml @65536
    float* sml = (float*)(smem + 65536);            // [128] float2 (1KB)

    const int t = threadIdx.x;
    const int lane = t & 63;
    const int wv = t >> 6;        // 0..7
    const int qg = wv & 3;        // 32-row query group (0..3)
    const int kh = wv >> 2;       // 32-key half (0..1)
    const int l16 = lane & 15;
    const int lg = lane >> 4;

    const int blk = blockIdx.x;
    const int x8 = blk & 7;
    const int b = x8 >> 1;                          // batch per XCD pair
    const int ksel = x8 & 1;                        // key half per XCD
    const int qt5 = blk >> 3;                       // 0..31
    const int n0 = qt5 << 7;                        // 128 q-rows per block
    const int kb = ksel << 11;                      // key base (0 or 2048)

    const _Float16* Kg = Kb + (size_t)b * 4096 * 128;
    const _Float16* Vg = Vb + (size_t)b * 256 * 4096;

    // ---- Q fragments for both q-tiles (rows qg*32+l16 and qg*32+16+l16)
    hfrag aq0[4], aq1[4];
    {
        const size_t gq0 = ((size_t)b * 4096 + n0 + qg * 32 + l16) * 128;
        const size_t gq1 = gq0 + 16 * 128;
#pragma unroll
        for (int st = 0; st < 4; ++st) {
            aq0[st] = *(const hfrag*)&Qb[gq0 + st * 32 + lg * 8];
            aq1[st] = *(const hfrag*)&Qb[gq1 + st * 32 + lg * 8];
        }
    }

    float m0 = -3e38f, l0 = 0.f;      // q-row r0 = qg*32 + l16
    float m1 = -3e38f, l1 = 0.f;      // q-row r1 = r0 + 16
    ffrag O0[16], O1[16];             // O^T[co = ct*16+lg*4+r][q]
#pragma unroll
    for (int i = 0; i < 16; ++i) {
        O0[i] = ffrag{0.f, 0.f, 0.f, 0.f};
        O1[i] = ffrag{0.f, 0.f, 0.f, 0.f};
    }
    hfrag pb0p, pb1p;                 // P fragments of iter i-1 (deferred PV)

    // staging lane constants
    const int krow_in = lane >> 4;              // K: row-in-chunk (0..3)
    const int kcol = lane & 15;                 // K: col chunk index
    const int vrow_in = lane >> 3;              // V: row-in-chunk (0..7)
    const int vcol = lane & 7;                  // V: col chunk index

    // stage K tile `it` into K buf bsel: 2 loads/wave
    auto STAGEK = [&](int it, int bsel) {
        const int k0 = kb + (it << 6);
        _Float16* sK = smem + (bsel << 13);
#pragma unroll
        for (int j = 0; j < 2; ++j) {
            const int c = 2 * wv + j;           // 0..15
            const int row = 4 * c + krow_in;
            gload_lds16(Kg + (size_t)(k0 + row) * 128 + ((kcol ^ (row & 7)) << 3),
                        sK + c * 512);
        }
    };
    // stage V tile `it` into V buf vb (0..2): 4 loads/wave
    auto STAGEV = [&](int it, int vb) {
        const int k0 = kb + (it << 6);
        _Float16* sV = smem + 16384 + (vb << 14);
#pragma unroll
        for (int j = 0; j < 4; ++j) {
            const int cv = 4 * wv + j;          // 0..31
            const int co = 8 * cv + vrow_in;
            gload_lds16(Vg + (size_t)co * 4096 + k0 + ((vcol ^ (co & 7)) << 3),
                        sV + cv * 512);
        }
    };

    // deferred PV: O += V(it-1) P(it-1)^T  (reads V buf (it-1)%3)
    auto PV = [&](int vb) {
        const _Float16* sV = smem + 16384 + (vb << 14);
#pragma unroll
        for (int ct = 0; ct < 16; ++ct) {
            const int co = ct * 16 + l16;
            hfrag av = *(const hfrag*)&sV[co * 64 + ((kh * 32 + lg * 8) ^ ((co & 7) << 3))];
            O0[ct] = MFMAH(av, pb0p, O0[ct]);
            O1[ct] = MFMAH(av, pb1p, O1[ct]);
        }
    };

    // ---- prologue: stage K(0) -> Kbuf0, V(0) -> Vbuf0
    STAGEK(0, 0);
    STAGEV(0, 0);
    __builtin_amdgcn_sched_barrier(0);

    int vbp = 2;     // (it-1)%3, unused at it=0
    int vbn = 1;     // (it+1)%3
#pragma unroll 1
    for (int it = 0; it < 32; ++it) {
        asm volatile("s_waitcnt vmcnt(4)" ::: "memory");   // K(it)+V(it-1) landed
        __builtin_amdgcn_s_barrier();                      // single barrier/iter
        __builtin_amdgcn_sched_barrier(0);
        STAGEK((it + 1) & 31, (it + 1) & 1);               // early K prefetch
        __builtin_amdgcn_sched_barrier(0);

        const _Float16* sK = smem + ((it & 1) << 13);

        __builtin_amdgcn_s_setprio(1);
        // ---- S^T = K Q^T, 2 q-tiles share each K fragment
        ffrag S00 = ffrag{0.f,0.f,0.f,0.f}, S01 = ffrag{0.f,0.f,0.f,0.f};
        ffrag S10 = ffrag{0.f,0.f,0.f,0.f}, S11 = ffrag{0.f,0.f,0.f,0.f};
#pragma unroll
        for (int kt = 0; kt < 2; ++kt) {
            const int rowk = kh * 32 + kt * 16 + l16;
            const int swz = (rowk & 7) << 3;
#pragma unroll
            for (int st = 0; st < 4; ++st) {
                hfrag ak = *(const hfrag*)&sK[rowk * 128 + ((st * 32 + lg * 8) ^ swz)];
                if (kt == 0) {
                    S00 = MFMAH(ak, aq0[st], S00);
                    S10 = MFMAH(ak, aq1[st], S10);
                } else {
                    S01 = MFMAH(ak, aq0[st], S01);
                    S11 = MFMAH(ak, aq1[st], S11);
                }
            }
        }
        // ---- deferred PV(it-1): MFMA cluster independent of softmax(it)
        if (it > 0) PV(vbp);
        __builtin_amdgcn_s_setprio(0);

        // ---- online softmax per q-row (2 rows/lane), defer-max THR=8
        float mx0 = fmaxf(fmaxf(fmaxf(S00[0], S00[1]), fmaxf(S00[2], S00[3])),
                          fmaxf(fmaxf(S01[0], S01[1]), fmaxf(S01[2], S01[3])));
        float mx1 = fmaxf(fmaxf(fmaxf(S10[0], S10[1]), fmaxf(S10[2], S10[3])),
                          fmaxf(fmaxf(S11[0], S11[1]), fmaxf(S11[2], S11[3])));
        mx0 = fmaxf(mx0, __shfl_xor(mx0, 16));
        mx0 = fmaxf(mx0, __shfl_xor(mx0, 32));
        mx1 = fmaxf(mx1, __shfl_xor(mx1, 16));
        mx1 = fmaxf(mx1, __shfl_xor(mx1, 32));
        if (__any((mx0 > m0 + 8.f) || (mx1 > m1 + 8.f))) {   // rare
            const float nm0 = fmaxf(m0, mx0), nm1 = fmaxf(m1, mx1);
            const float sc0 = __expf(m0 - nm0), sc1 = __expf(m1 - nm1);
            m0 = nm0; m1 = nm1;
            l0 *= sc0; l1 *= sc1;
#pragma unroll
            for (int i = 0; i < 16; ++i) {
#pragma unroll
                for (int r = 0; r < 4; ++r) {
                    O0[i][r] *= sc0;
                    O1[i][r] *= sc1;
                }
            }
        }
        float e00[4], e01[4], e10[4], e11[4];
        float rs0 = 0.f, rs1 = 0.f;
#pragma unroll
        for (int r = 0; r < 4; ++r) {
            e00[r] = __expf(S00[r] - m0);
            e01[r] = __expf(S01[r] - m0);
            e10[r] = __expf(S10[r] - m1);
            e11[r] = __expf(S11[r] - m1);
            rs0 += e00[r] + e01[r];
            rs1 += e10[r] + e11[r];
        }
        rs0 += __shfl_xor(rs0, 16);
        rs0 += __shfl_xor(rs0, 32);
        rs1 += __shfl_xor(rs1, 16);
        rs1 += __shfl_xor(rs1, 32);
        l0 += rs0;
        l1 += rs1;

        // ---- pack P(it) lane-locally (overwrites prev AFTER PV consumed it)
        {
            union { int i[4]; hfrag h; } u;
            u.i[0] = pkh(e00[0], e00[1]);
            u.i[1] = pkh(e00[2], e00[3]);
            u.i[2] = pkh(e01[0], e01[1]);
            u.i[3] = pkh(e01[2], e01[3]);
            pb0p = u.h;
            u.i[0] = pkh(e10[0], e10[1]);
            u.i[1] = pkh(e10[2], e10[3]);
            u.i[2] = pkh(e11[0], e11[1]);
            u.i[3] = pkh(e11[2], e11[3]);
            pb1p = u.h;
        }

        // ---- late V prefetch into buf (it+1)%3 (WAR safe: last reader was
        //      PV(it-2) in iter it-1, separated by this iter's barrier)
        STAGEV((it + 1) & 31, vbn);
        __builtin_amdgcn_sched_barrier(0);

        vbp = (vbp == 2) ? 0 : vbp + 1;
        vbn = (vbn == 2) ? 0 : vbn + 1;
    }

    // ---- drain wrapped stages, then final PV(31) (V buf 31%3 = 1)
    asm volatile("s_waitcnt vmcnt(0)" ::: "memory");
    __builtin_amdgcn_s_barrier();
    PV(1);

    // ---- epilogue: kh merge via fp16 LDS overlay, write pO/pML ----
    __syncthreads();
    _Float16* sE = smem;               // [128 row][256 col] fp16 (0..32767: K0,K1,V0)
    const int r0 = qg * 32 + l16;      // this lane's q-rows (0..127)
    const int r1 = r0 + 16;
    const int rsw0 = (r0 & 7) << 3;
    const int rsw1 = (r1 & 7) << 3;
    if (kh == 1) {
        const float inv0 = 1.f / l0, inv1 = 1.f / l1;
#pragma unroll
        for (int ct = 0; ct < 16; ++ct)
#pragma unroll
            for (int r = 0; r < 4; ++r) {
                const int col = ct * 16 + lg * 4 + r;
                sE[r0 * 256 + (col ^ rsw0)] = (_Float16)(O0[ct][r] * inv0);
                sE[r1 * 256 + (col ^ rsw1)] = (_Float16)(O1[ct][r] * inv1);
            }
        if (lg == 0) {
            ((float2*)sml)[r0] = make_float2(m0, l0);
            ((float2*)sml)[r1] = make_float2(m1, l1);
        }
    }
    __syncthreads();
    const size_t mlbase = (size_t)(ksel * 4 + b) * 4096 + n0;
    if (kh == 0) {
        const float2 pml0 = ((const float2*)sml)[r0];
        const float2 pml1 = ((const float2*)sml)[r1];
        const float M0 = fmaxf(m0, pml0.x), M1 = fmaxf(m1, pml1.x);
        const float a0 = __expf(m0 - M0), c0 = __expf(pml0.x - M0);
        const float a1 = __expf(m1 - M1), c1 = __expf(pml1.x - M1);
        const float nl0 = a0 * l0 + c0 * pml0.y;
        const float nl1 = a1 * l1 + c1 * pml1.y;
        const float wa0 = a0 / nl0, wb0 = c0 * pml0.y / nl0;
        const float wa1 = a1 / nl1, wb1 = c1 * pml1.y / nl1;
        if (lg == 0) {
            ((float2*)pML)[mlbase + r0] = make_float2(M0, nl0);
            ((float2*)pML)[mlbase + r1] = make_float2(M1, nl1);
        }
#pragma unroll
        for (int ct = 0; ct < 16; ++ct)
#pragma unroll
            for (int r = 0; r < 4; ++r) {
                const int col = ct * 16 + lg * 4 + r;
                const int i0 = r0 * 256 + (col ^ rsw0);
                const int i1 = r1 * 256 + (col ^ rsw1);
                const float v0 = (float)sE[i0];
                const float v1 = (float)sE[i1];
                sE[i0] = (_Float16)(wa0 * O0[ct][r] + wb0 * v0);
                sE[i1] = (_Float16)(wa1 * O1[ct][r] + wb1 * v1);
            }
    }
    __syncthreads();
    // ---- cooperative coalesced 16B store of the 64KB tile (unswizzle)
    const size_t obase = ((size_t)(ksel * 4 + b) * 4096 + n0) * 256;
#pragma unroll
    for (int i = 0; i < 8; ++i) {
        const int idx = i * 512 + t;            // 0..4095
        const int px = idx >> 5;                // 0..127
        const int cg = idx & 31;                // col-group of 8
        *(us8*)&pO[obase + (size_t)px * 256 + cg * 8] =
            *(const us8*)&sE[px * 256 + (cg ^ (px & 7)) * 8];
    }
}

// ---------------------------------------------------------------------------
// Kernel 4: cross-block flash merge of the two key-halves + BN partial sums.
// 256 blocks x 256 threads; block = 64 rows.  Deterministic.
// ---------------------------------------------------------------------------
__global__ __launch_bounds__(256) void kmerge(const _Float16* __restrict__ pO,
                                              const float* __restrict__ pML,
                                              _Float16* __restrict__ wbuf,
                                              float* __restrict__ part) {
    __shared__ float sacc[2048];    // [8 rowloc][256 co]
    __shared__ float sacc2[2048];
    const int t = threadIdx.x;
    const int rowloc = t >> 5;          // 0..7
    const int co8 = (t & 31) * 8;
    float s[8], s2[8];
#pragma unroll
    for (int j = 0; j < 8; ++j) { s[j] = 0.f; s2[j] = 0.f; }
#pragma unroll 2
    for (int i = 0; i < 8; ++i) {
        const int g = blockIdx.x * 64 + i * 8 + rowloc;     // 0..16383
        const float2 ml0 = ((const float2*)pML)[g];
        const float2 ml1 = ((const float2*)pML)[16384 + g];
        const float M = fmaxf(ml0.x, ml1.x);
        const float a = __expf(ml0.x - M) * ml0.y;
        const float c = __expf(ml1.x - M) * ml1.y;
        const float inv = 1.f / (a + c);
        const float wa = a * inv, wc = c * inv;
        hfrag o0 = *(const hfrag*)&pO[(size_t)g * 256 + co8];
        hfrag o1 = *(const hfrag*)&pO[(size_t)(16384 + g) * 256 + co8];
        hfrag w;
#pragma unroll
        for (int j = 0; j < 8; ++j) {
            const float v = wa * (float)o0[j] + wc * (float)o1[j];
            w[j] = (_Float16)v;
            s[j] += v;
            s2[j] += v * v;
        }
        *(hfrag*)&wbuf[(size_t)g * 256 + co8] = w;
    }
#pragma unroll
    for (int j = 0; j < 8; ++j) {
        sacc[rowloc * 256 + co8 + j] = s[j];
        sacc2[rowloc * 256 + co8 + j] = s2[j];
    }
    __syncthreads();
    float p = 0.f, p2 = 0.f;
#pragma unroll
    for (int rl = 0; rl < 8; ++rl) {
        p  += sacc[rl * 256 + t];
        p2 += sacc2[rl * 256 + t];
    }
    part[blockIdx.x * 512 + t] = p;
    part[blockIdx.x * 512 + 256 + t] = p2;
}

// Kernel 4b: reduce partials -> stats[512]. 512 blocks x 64 lanes,
// deterministic fixed-tree shuffle reduce over 256 partial blocks.
__global__ void kstats2(const float* __restrict__ partial, float* __restrict__ stats) {
    const int ch = blockIdx.x;        // 0..511
    const int j = threadIdx.x;        // 0..63
    float s = 0.f;
#pragma unroll
    for (int i = 0; i < 4; ++i)
        s += partial[(size_t)(j + 64 * i) * 512 + ch];
    s += __shfl_xor(s, 1);
    s += __shfl_xor(s, 2);
    s += __shfl_xor(s, 4);
    s += __shfl_xor(s, 8);
    s += __shfl_xor(s, 16);
    s += __shfl_xor(s, 32);
    if (j == 0) stats[ch] = s;
}

// ---------------------------------------------------------------------------
// Kernel 5: apply BN + transpose [b][n][co] -> out[b][co][n] fp32.
// ---------------------------------------------------------------------------
__global__ __launch_bounds__(256) void kapply(const _Float16* __restrict__ w,
                                              const float* __restrict__ stats,
                                              const float* __restrict__ gamma,
                                              const float* __restrict__ beta,
                                              float* __restrict__ out) {
    __shared__ _Float16 sw[64 * 260];           // 64 rows, pad 256->260
    __shared__ float sscale[256];
    __shared__ float sshift[256];
    const int t = threadIdx.x;
    const int b = blockIdx.x >> 6;
    const int n0 = (blockIdx.x & 63) << 6;
    const _Float16* wb = w + ((size_t)b * 4096 + n0) * 256;
#pragma unroll
    for (int i = 0; i < 16; ++i) {
        const int chunk = i * 256 + t;
        const int p = chunk >> 6;
        const int cq = chunk & 63;
        *(us4*)&sw[p * 260 + cq * 4] = *(const us4*)&wb[p * 256 + cq * 4];
    }
    {
        const float mean = stats[t] * (1.f / 16384.f);
        const float var = stats[256 + t] * (1.f / 16384.f) - mean * mean;
        const float inv = rsqrtf(var + 1e-5f);
        const float sc = gamma[t] * inv;
        sscale[t] = sc;
        sshift[t] = beta[t] - mean * sc;
    }
    __syncthreads();
    const int p = t & 63;
    const int cg = t >> 6;
    float* ob = out + (size_t)b * 256 * 4096 + n0;
#pragma unroll 4
    for (int i = 0; i < 64; ++i) {
        const int co = i * 4 + cg;
        const float v = (float)sw[p * 260 + co];
        ob[(size_t)co * 4096 + p] = v * sscale[co] + sshift[co];
    }
}

// ---------------------------------------------------------------------------
extern "C" void kernel_launch(void* const* d_in, const int* in_sizes, int n_in,
                              void* d_out, int out_size, void* d_ws, size_t ws_size,
                              hipStream_t stream) {
    const float* x     = (const float*)d_in[0];
    const float* Wq    = (const float*)d_in[1];
    const float* bq    = (const float*)d_in[2];
    const float* Wk    = (const float*)d_in[3];
    const float* bk    = (const float*)d_in[4];
    const float* Wv    = (const float*)d_in[5];
    const float* bv    = (const float*)d_in[6];
    const float* gamma = (const float*)d_in[7];
    const float* beta  = (const float*)d_in[8];
    float* out = (float*)d_out;

    char* ws = (char*)d_ws;
    // lifetimes: Wh/ball [kprep->kproj]; pML aliases Wh [kattn->kmerge];
    // Qb/Kb [kproj->kattn]; wbuf aliases Qb+Kb [kmerge->kapply].
    _Float16* Wh    = (_Float16*)(ws + 0x0);        // 256 KB
    float*    pML   = (float*)(ws + 0x0);           // 256 KB (2x4x4096 float2)
    float*    ball  = (float*)(ws + 0x40000);       // 2 KB
    float*    stats = (float*)(ws + 0x40800);       // 2 KB
    float*    part  = (float*)(ws + 0x41000);       // 512 KB (256 x 512 f32)
    _Float16* Qb    = (_Float16*)(ws + 0x100000);   // 4 MB
    _Float16* Kb    = (_Float16*)(ws + 0x500000);   // 4 MB
    _Float16* wbuf  = (_Float16*)(ws + 0x100000);   // 8 MB over Qb+Kb
    _Float16* Vb    = (_Float16*)(ws + 0x900000);   // 8 MB
    _Float16* pO    = (_Float16*)(ws + 0x1100000);  // 16 MB (2x4x4096x256 fp16)
    if (ws_size < 0x2100000) return;  // 33 MB scratch (verified available)

    kprep<<<512, 256, 0, stream>>>(Wq, Wk, Wv, bq, bk, bv, Wh, ball);
    kproj<<<256, 256, 0, stream>>>(x, Wh, ball, Qb, Kb, Vb);
    kattn<<<256, 512, 0, stream>>>(Qb, Kb, Vb, pO, pML);
    kmerge<<<256, 256, 0, stream>>>(pO, pML, wbuf, part);
    kstats2<<<512, 64, 0, stream>>>(part, stats);
    kapply<<<256, 256, 0, stream>>>(wbuf, stats, gamma, beta, out);
}